// Round 19
// baseline (178.374 us; speedup 1.0000x reference)
//
#include <hip/hip_runtime.h>

constexpr int CB = 2, CL = 1024, CD = 1024, CNH = 16, CHD = 64, CHDH = 128, CBN = CB * CNH;

__device__ __forceinline__ float sigf(float x) { return 1.0f / (1.0f + __expf(-x)); }

__device__ __forceinline__ unsigned short f2bf(float x) {
    unsigned u = __float_as_uint(x);
    u += 0x7fffu + ((u >> 16) & 1u);
    return (unsigned short)(u >> 16);
}
__device__ __forceinline__ unsigned pk2(float a, float b) {
    return (unsigned)f2bf(a) | ((unsigned)f2bf(b) << 16);
}
__device__ __forceinline__ unsigned pkus(unsigned short a, unsigned short b) {
    return (unsigned)a | ((unsigned)b << 16);
}
__device__ __forceinline__ float bf2f(unsigned short u) {
    return __uint_as_float(((unsigned)u) << 16);
}

typedef __attribute__((ext_vector_type(8))) short short8v;
typedef __attribute__((ext_vector_type(4))) float f32x4;
#define MFMA16(a, b, c) __builtin_amdgcn_mfma_f32_16x16x32_bf16(a, b, c, 0, 0, 0)

// ---------------------------------------------------------------------------
// Merged conversions.
// ---------------------------------------------------------------------------
__global__ __launch_bounds__(256) void conv_kernel(
    const float* __restrict__ x, const float* __restrict__ qw,
    const float* __restrict__ kw, const float* __restrict__ vw,
    const float* __restrict__ W1, const float* __restrict__ W2,
    const float* __restrict__ ow, unsigned short* __restrict__ xb,
    unsigned short* __restrict__ qwb, unsigned short* __restrict__ kwb,
    unsigned short* __restrict__ vwb, unsigned short* __restrict__ w1b,
    unsigned short* __restrict__ w2b, unsigned short* __restrict__ w2t,
    unsigned short* __restrict__ owh, unsigned short* __restrict__ owl) {
    int i = blockIdx.x * 256 + threadIdx.x;
    if (i < 1310720) {
        const float* s;
        unsigned short* d;
        int off;
        if (i < 524288) { s = x; d = xb; off = i; }
        else if (i < 786432) { s = qw; d = qwb; off = i - 524288; }
        else if (i < 1048576) { s = kw; d = kwb; off = i - 786432; }
        else { s = vw; d = vwb; off = i - 1048576; }
        float4 v = *(const float4*)(s + (size_t)off * 4);
        *(uint2*)(d + (size_t)off * 4) = make_uint2(pk2(v.x, v.y), pk2(v.z, v.w));
    } else if (i < 1507328) {
        int j = i - 1310720;
        if (j < 65536) {
            size_t e = (size_t)j * 4;
            float4 v = *(const float4*)(W1 + e);
            *(uint2*)(w1b + e) = make_uint2(pk2(v.x, v.y), pk2(v.z, v.w));
        } else if (j < 131072) {
            size_t e = (size_t)(j - 65536) * 4;
            float4 v = *(const float4*)(W2 + e);
            *(uint2*)(w2b + e) = make_uint2(pk2(v.x, v.y), pk2(v.z, v.w));
        } else {
            size_t e = (size_t)(j - 131072) * 4;
            int bn = (int)(e >> 13), rem = (int)(e & 8191);
            int h = rem >> 6, d0 = rem & 63;
            const float* src = W2 + (size_t)bn * CHD * CHDH;
            float a = src[(d0 + 0) * CHDH + h], b = src[(d0 + 1) * CHDH + h];
            float c = src[(d0 + 2) * CHDH + h], dd = src[(d0 + 3) * CHDH + h];
            *(uint2*)(w2t + e) = make_uint2(pk2(a, b), pk2(c, dd));
        }
    } else {
        size_t e = (size_t)(i - 1507328) * 4;
        float4 v = *(const float4*)(ow + e);
        unsigned short h0 = f2bf(v.x), h1 = f2bf(v.y), h2 = f2bf(v.z), h3 = f2bf(v.w);
        *(uint2*)(owh + e) = make_uint2(pkus(h0, h1), pkus(h2, h3));
        *(uint2*)(owl + e) = make_uint2(
            pk2(v.x - bf2f(h0), v.y - bf2f(h1)), pk2(v.z - bf2f(h2), v.w - bf2f(h3)));
    }
}

// ---------------------------------------------------------------------------
// Merged q/k/v projection GEMM: 64x128 tile, K=1024, 512 threads.
// Grid (24 col-tiles, 32 row-tiles) = 768 blocks = 3/CU uniform.
// ---------------------------------------------------------------------------
__global__ __launch_bounds__(512) void qkv_mfma(
    const unsigned short* __restrict__ xbf, const unsigned short* __restrict__ wqkv,
    const float* __restrict__ qb, const float* __restrict__ kb,
    const float* __restrict__ vb, unsigned short* __restrict__ qbf,
    unsigned short* __restrict__ kbf, unsigned short* __restrict__ ktbf,
    float* __restrict__ vhb) {
    __shared__ __align__(16) unsigned short SM[16896];  // 33792 B
    unsigned short(*Ab)[72] = (unsigned short(*)[72])SM;           // [64][72]
    unsigned short(*Bb)[72] = (unsigned short(*)[72])(SM + 4608);  // [128][72]
    const int t = threadIdx.x;
    const int c0 = blockIdx.x << 7, r0 = blockIdx.y << 6;
    const int wv = t >> 6, lane = t & 63;
    const int lm = lane & 15, lg = lane >> 4;
    f32x4 acc[4];
#pragma unroll
    for (int i = 0; i < 4; ++i) acc[i] = (f32x4){0.f, 0.f, 0.f, 0.f};
    for (int kc = 0; kc < CD; kc += 64) {
        for (int i = t; i < 512; i += 512) {
            int r = i >> 3, c = (i & 7) * 8;
            *(uint4*)&Ab[r][c] = *(const uint4*)(xbf + (size_t)(r0 + r) * CD + kc + c);
        }
        for (int i = t; i < 1024; i += 512) {
            int r = i >> 3, c = (i & 7) * 8;
            *(uint4*)&Bb[r][c] = *(const uint4*)(wqkv + (size_t)(c0 + r) * CD + kc + c);
        }
        __syncthreads();
#pragma unroll
        for (int m16 = 0; m16 < 4; ++m16)
#pragma unroll
            for (int ks = 0; ks < 2; ++ks) {
                short8v a = *(const short8v*)&Ab[m16 * 16 + lm][ks * 32 + lg * 8];
                short8v b = *(const short8v*)&Bb[wv * 16 + lm][ks * 32 + lg * 8];
                acc[m16] = MFMA16(a, b, acc[m16]);
            }
        __syncthreads();
    }
    const int which = c0 >> 10;
    const int ccb = c0 & 1023;
    const float* bias = which == 0 ? qb : (which == 1 ? kb : vb);
    const int b = r0 >> 10, lb0 = r0 & 1023;
    float(*Os)[132] = (float(*)[132])SM;  // 64x132 f32 = 33792 B (exact overlay)
    {
        int col = wv * 16 + lm;
        float bb = bias[ccb + col];
#pragma unroll
        for (int m16 = 0; m16 < 4; ++m16)
#pragma unroll
            for (int r = 0; r < 4; ++r)
                Os[m16 * 16 + lg * 4 + r][col] = acc[m16][r] + bb;
    }
    __syncthreads();
    if (which == 2) {
        for (int i = t; i < 2048; i += 512) {
            int r = i >> 5, c = (i & 31) * 4;
            int n = (ccb + c) >> 6, d = (ccb + c) & 63;
            *(float4*)(vhb + (((size_t)b * CNH + n) * CL + lb0 + r) * 64 + d) =
                *(const float4*)&Os[r][c];
        }
    } else {
        unsigned short* dst = which == 0 ? qbf : kbf;
        for (int i = t; i < 2048; i += 512) {
            int r = i >> 5, c = (i & 31) * 4;
            int n = (ccb + c) >> 6, d = (ccb + c) & 63;
            float4 v4 = *(const float4*)&Os[r][c];
            *(uint2*)(dst + (((size_t)b * CNH + n) * CL + lb0 + r) * 64 + d) =
                make_uint2(pk2(v4.x, v4.y), pk2(v4.z, v4.w));
        }
        if (which == 1) {
            for (int i = t; i < 1024; i += 512) {
                int col = i >> 3, lb = (i & 7) * 8;
                int n = (ccb + col) >> 6, d = (ccb + col) & 63;
                uint4 u;
                u.x = pk2(Os[lb + 0][col], Os[lb + 1][col]);
                u.y = pk2(Os[lb + 2][col], Os[lb + 3][col]);
                u.z = pk2(Os[lb + 4][col], Os[lb + 5][col]);
                u.w = pk2(Os[lb + 6][col], Os[lb + 7][col]);
                *(uint4*)(ktbf + (((size_t)b * CNH + n) * 64 + d) * CL + lb0 + lb) = u;
            }
        }
    }
}

// ---------------------------------------------------------------------------
// Split-precision MFMA o-projection: A pre-split bf16 (zh,zl), plain staging.
// Grid (32 rows, 8 cols): blocks sharing a row-panel land on one XCD.
// ---------------------------------------------------------------------------
__global__ __launch_bounds__(512) void gemm_obf(const unsigned short* __restrict__ zh,
                                                const unsigned short* __restrict__ zl,
                                                const unsigned short* __restrict__ Bh,
                                                const unsigned short* __restrict__ Bl,
                                                const float* __restrict__ bias,
                                                float* __restrict__ C) {
    __shared__ __align__(16) unsigned short SM[27648];
    unsigned short(*Ah)[72] = (unsigned short(*)[72])SM;            // [64][72]
    unsigned short(*Al)[72] = (unsigned short(*)[72])(SM + 4608);   // [64][72]
    unsigned short(*Bhs)[72] = (unsigned short(*)[72])(SM + 9216);  // [128][72]
    unsigned short(*Bls)[72] = (unsigned short(*)[72])(SM + 18432); // [128][72]
    const int t = threadIdx.x;
    const int r0 = blockIdx.x << 6, c0 = blockIdx.y << 7;
    const int wv = t >> 6, lane = t & 63;
    const int lm = lane & 15, lg = lane >> 4;
    const int b = r0 >> 10, lb0 = r0 & 1023;
    f32x4 acc[4];
#pragma unroll
    for (int i = 0; i < 4; ++i) acc[i] = (f32x4){0.f, 0.f, 0.f, 0.f};
    for (int kc = 0; kc < CD; kc += 64) {
        const int n = kc >> 6;
        const size_t abase = (((size_t)b * CNH + n) * CL + lb0) * 64;
        for (int i = t; i < 512; i += 512) {
            int r = i >> 3, c = (i & 7) * 8;
            *(uint4*)&Ah[r][c] = *(const uint4*)(zh + abase + (size_t)r * 64 + c);
            *(uint4*)&Al[r][c] = *(const uint4*)(zl + abase + (size_t)r * 64 + c);
        }
        for (int i = t; i < 1024; i += 512) {
            int r = i >> 3, c = (i & 7) * 8;
            *(uint4*)&Bhs[r][c] = *(const uint4*)(Bh + (size_t)(c0 + r) * CD + kc + c);
            *(uint4*)&Bls[r][c] = *(const uint4*)(Bl + (size_t)(c0 + r) * CD + kc + c);
        }
        __syncthreads();
#pragma unroll
        for (int m16 = 0; m16 < 4; ++m16)
#pragma unroll
            for (int ks = 0; ks < 2; ++ks) {
                short8v ah = *(const short8v*)&Ah[m16 * 16 + lm][ks * 32 + lg * 8];
                short8v al = *(const short8v*)&Al[m16 * 16 + lm][ks * 32 + lg * 8];
                short8v bh = *(const short8v*)&Bhs[wv * 16 + lm][ks * 32 + lg * 8];
                short8v bl = *(const short8v*)&Bls[wv * 16 + lm][ks * 32 + lg * 8];
                acc[m16] = MFMA16(ah, bh, acc[m16]);
                acc[m16] = MFMA16(ah, bl, acc[m16]);
                acc[m16] = MFMA16(al, bh, acc[m16]);
            }
        __syncthreads();
    }
    float(*Os)[132] = (float(*)[132])SM;
    {
        int col = wv * 16 + lm;
        float bb = bias[c0 + col];
#pragma unroll
        for (int m16 = 0; m16 < 4; ++m16)
#pragma unroll
            for (int r = 0; r < 4; ++r)
                Os[m16 * 16 + lg * 4 + r][col] = acc[m16][r] + bb;
    }
    __syncthreads();
    for (int i = t; i < 2048; i += 512) {
        int r = i >> 5, c = (i & 31) * 4;
        *(float4*)(C + (size_t)(r0 + r) * CD + c0 + c) = *(const float4*)&Os[r][c];
    }
}

// ---------------------------------------------------------------------------
// lr / log_wd projections.
// ---------------------------------------------------------------------------
__global__ __launch_bounds__(64) void lrwd_kernel(
    const float* __restrict__ x, const float* __restrict__ lblr,
    const float* __restrict__ fclr_w, const float* __restrict__ fclr_b,
    const float* __restrict__ lbwd, const float* __restrict__ fcwd_w,
    const float* __restrict__ fcwd_b, float* __restrict__ lrp,
    float* __restrict__ logwd) {
    const int r = blockIdx.x;
    const int b = r >> 10, l = r & 1023;
    const int lane = threadIdx.x;
    float xv[16];
#pragma unroll
    for (int j = 0; j < 16; ++j) xv[j] = x[(size_t)r * CD + lane + 64 * j];
    for (int n = 0; n < CNH; ++n) {
        float d1 = 0.f, d2 = 0.f;
#pragma unroll
        for (int j = 0; j < 16; ++j) {
            d1 += xv[j] * fclr_w[(size_t)n * CD + lane + 64 * j];
            d2 += xv[j] * fcwd_w[(size_t)n * CD + lane + 64 * j];
        }
#pragma unroll
        for (int s = 32; s > 0; s >>= 1) {
            d1 += __shfl_down(d1, s);
            d2 += __shfl_down(d2, s);
        }
        if (lane == 0) {
            lrp[((size_t)b * CNH + n) * CL + l] = __expf(lblr[n]) * sigf(d1 + fclr_b[n]);
            logwd[((size_t)b * CNH + n) * CL + l] =
                log1pf(-__expf(lbwd[n]) * sigf(d2 + fcwd_b[n]));
        }
    }
}

// ---------------------------------------------------------------------------
// Inclusive prefix sum of log_wd -> cum, plus wdc = exp(cum).
// ---------------------------------------------------------------------------
__global__ __launch_bounds__(64) void scan_kernel(float* __restrict__ cum,
                                                  float* __restrict__ wdc) {
    const int bn = blockIdx.x;
    const int lane = threadIdx.x;
    float* p = cum + (size_t)bn * CL;
    float v[16];
#pragma unroll
    for (int j = 0; j < 16; ++j) v[j] = p[lane * 16 + j];
#pragma unroll
    for (int j = 1; j < 16; ++j) v[j] += v[j - 1];
    float tot = v[15];
    float inc = tot;
#pragma unroll
    for (int s = 1; s < 64; s <<= 1) {
        float tv = __shfl_up(inc, s);
        if (lane >= s) inc += tv;
    }
    const float pre = inc - tot;
#pragma unroll
    for (int j = 0; j < 16; ++j) {
        float c = pre + v[j];
        p[lane * 16 + j] = c;
        wdc[(size_t)bn * CL + lane * 16 + j] = __expf(c);
    }
}

// ---------------------------------------------------------------------------
// MFMA MLP fwd/bwd over 64 tokens.
// ---------------------------------------------------------------------------
__global__ __launch_bounds__(256) void mlp_mfma(
    const unsigned short* __restrict__ kbf, const float* __restrict__ vh,
    const unsigned short* __restrict__ w1bf, const unsigned short* __restrict__ w2bf,
    const unsigned short* __restrict__ w2tbf, unsigned short* __restrict__ x2bf,
    unsigned short* __restrict__ x2t, unsigned short* __restrict__ gz1t,
    unsigned short* __restrict__ gz2t) {
    __shared__ __align__(16) unsigned short RA[128][72];
    __shared__ __align__(16) unsigned short RB[64][72];
    __shared__ __align__(16) unsigned short RC[64][136];
    __shared__ __align__(16) unsigned short X2s[64][136];
    const int bn = blockIdx.y, l0 = blockIdx.x << 6;
    const int t = threadIdx.x;
    const int wv = t >> 6, lane = t & 63;
    const int lm = lane & 15, lg = lane >> 4;
    {
        const unsigned short* kg = kbf + ((size_t)bn * CL + l0) * CHD;
        for (int i = t; i < 512; i += 256) {
            int r = i >> 3, c = (i & 7) * 8;
            *(uint4*)&RB[r][c] = *(const uint4*)(kg + (size_t)r * CHD + c);
        }
        const unsigned short* w1g = w1bf + (size_t)bn * CHDH * CHD;
        for (int i = t; i < 1024; i += 256) {
            int r = i >> 3, c = (i & 7) * 8;
            *(uint4*)&RA[r][c] = *(const uint4*)(w1g + (size_t)r * CHD + c);
        }
        const unsigned short* w2g = w2bf + (size_t)bn * CHD * CHDH;
        for (int i = t; i < 1024; i += 256) {
            int r = i >> 4, c = (i & 15) * 8;
            *(uint4*)&RC[r][c] = *(const uint4*)(w2g + (size_t)r * CHDH + c);
        }
    }
    __syncthreads();
    f32x4 acc1[4][2];
#pragma unroll
    for (int i = 0; i < 4; ++i)
#pragma unroll
        for (int j = 0; j < 2; ++j) acc1[i][j] = (f32x4){0.f, 0.f, 0.f, 0.f};
#pragma unroll
    for (int m16 = 0; m16 < 4; ++m16)
#pragma unroll
        for (int hh = 0; hh < 2; ++hh) {
            int h16 = wv * 2 + hh;
#pragma unroll
            for (int ks = 0; ks < 2; ++ks) {
                short8v a = *(const short8v*)&RB[m16 * 16 + lm][ks * 32 + lg * 8];
                short8v b = *(const short8v*)&RA[h16 * 16 + lm][ks * 32 + lg * 8];
                acc1[m16][hh] = MFMA16(a, b, acc1[m16][hh]);
            }
        }
#pragma unroll
    for (int m16 = 0; m16 < 4; ++m16)
#pragma unroll
        for (int hh = 0; hh < 2; ++hh)
#pragma unroll
            for (int r = 0; r < 4; ++r) {
                float a = acc1[m16][hh][r];
                X2s[m16 * 16 + lg * 4 + r][(wv * 2 + hh) * 16 + lm] = f2bf(a * sigf(a));
            }
    __syncthreads();
    {
        const unsigned short* w2tg = w2tbf + (size_t)bn * CHDH * CHD;
        for (int i = t; i < 1024; i += 256) {
            int r = i >> 3, c = (i & 7) * 8;
            *(uint4*)&RA[r][c] = *(const uint4*)(w2tg + (size_t)r * CHD + c);
        }
    }
    {
        f32x4 acc2[4];
#pragma unroll
        for (int i = 0; i < 4; ++i) acc2[i] = (f32x4){0.f, 0.f, 0.f, 0.f};
#pragma unroll
        for (int m16 = 0; m16 < 4; ++m16)
#pragma unroll
            for (int ks = 0; ks < 4; ++ks) {
                short8v a = *(const short8v*)&X2s[m16 * 16 + lm][ks * 32 + lg * 8];
                short8v b = *(const short8v*)&RC[wv * 16 + lm][ks * 32 + lg * 8];
                acc2[m16] = MFMA16(a, b, acc2[m16]);
            }
#pragma unroll
        for (int m16 = 0; m16 < 4; ++m16)
#pragma unroll
            for (int r = 0; r < 4; ++r) {
                int l = l0 + m16 * 16 + lg * 4 + r;
                float v = vh[((size_t)bn * CL + l) * 64 + wv * 16 + lm];
                RB[m16 * 16 + lg * 4 + r][wv * 16 + lm] = f2bf(acc2[m16][r] - v);
            }
    }
    __syncthreads();
#pragma unroll
    for (int m16 = 0; m16 < 4; ++m16)
#pragma unroll
        for (int hh = 0; hh < 2; ++hh) {
            int h16 = wv * 2 + hh;
            f32x4 p = (f32x4){0.f, 0.f, 0.f, 0.f};
#pragma unroll
            for (int ks = 0; ks < 2; ++ks) {
                short8v a = *(const short8v*)&RB[m16 * 16 + lm][ks * 32 + lg * 8];
                short8v b = *(const short8v*)&RA[h16 * 16 + lm][ks * 32 + lg * 8];
                p = MFMA16(a, b, p);
            }
#pragma unroll
            for (int r = 0; r < 4; ++r) {
                float zz = acc1[m16][hh][r];
                float s = sigf(zz);
                float sil = zz * s;
                RC[m16 * 16 + lg * 4 + r][h16 * 16 + lm] =
                    f2bf((sil + s * (1.f - sil)) * p[r]);
            }
        }
    __syncthreads();
    for (int i = t; i < 1024; i += 256) {
        int r = i >> 4, c = (i & 15) * 8;
        *(uint4*)(x2bf + ((size_t)bn * CL + l0 + r) * CHDH + c) = *(const uint4*)&X2s[r][c];
    }
    for (int i = t; i < 1024; i += 256) {
        int h = i >> 3, lb = (i & 7) * 8;
        uint4 u;
        u.x = pkus(X2s[lb + 0][h], X2s[lb + 1][h]);
        u.y = pkus(X2s[lb + 2][h], X2s[lb + 3][h]);
        u.z = pkus(X2s[lb + 4][h], X2s[lb + 5][h]);
        u.w = pkus(X2s[lb + 6][h], X2s[lb + 7][h]);
        *(uint4*)(x2t + ((size_t)bn * CHDH + h) * CL + l0 + lb) = u;
    }
    for (int i = t; i < 1024; i += 256) {
        int h = i >> 3, lb = (i & 7) * 8;
        uint4 u;
        u.x = pkus(RC[lb + 0][h], RC[lb + 1][h]);
        u.y = pkus(RC[lb + 2][h], RC[lb + 3][h]);
        u.z = pkus(RC[lb + 4][h], RC[lb + 5][h]);
        u.w = pkus(RC[lb + 6][h], RC[lb + 7][h]);
        *(uint4*)(gz1t + ((size_t)bn * CHDH + h) * CL + l0 + lb) = u;
    }
    for (int i = t; i < 512; i += 256) {
        int d = i >> 3, lb = (i & 7) * 8;
        uint4 u;
        u.x = pkus(RB[lb + 0][d], RB[lb + 1][d]);
        u.y = pkus(RB[lb + 2][d], RB[lb + 3][d]);
        u.z = pkus(RB[lb + 4][d], RB[lb + 5][d]);
        u.w = pkus(RB[lb + 6][d], RB[lb + 7][d]);
        *(uint4*)(gz2t + ((size_t)bn * CHD + d) * CL + l0 + lb) = u;
    }
}

// ---------------------------------------------------------------------------
// dsA1: per-chunk state delta for layer 1.
// ---------------------------------------------------------------------------
__global__ __launch_bounds__(256) void dsA1(
    const unsigned short* __restrict__ ktbf, const unsigned short* __restrict__ gz1t,
    const float* __restrict__ lrp, const float* __restrict__ cump,
    float* __restrict__ ds1, float* __restrict__ ds2) {
    __shared__ __align__(16) unsigned short Ab[64][72];
    __shared__ __align__(16) unsigned short Bb[128][72];
    __shared__ float coefA[64];
    const int c = blockIdx.x, bn = blockIdx.y, t = threadIdx.x;
    const int l0 = c << 6;
    const int wv = t >> 6, lane = t & 63;
    const int lm = lane & 15, lg = lane >> 4;
    const float Ac = cump[(size_t)bn * CL + l0];
    if (t < 64)
        coefA[t] = lrp[(size_t)bn * CL + l0 + t] *
                   __expf(Ac - cump[(size_t)bn * CL + l0 + t]);
    for (int i = t; i < 1024; i += 256) {
        int h = i >> 3, cc = (i & 7) * 8;
        *(uint4*)&Bb[h][cc] = *(const uint4*)(gz1t + ((size_t)bn * CHDH + h) * CL + l0 + cc);
    }
    __syncthreads();
    for (int i = t; i < 512; i += 256) {
        int d = i >> 3, cc = (i & 7) * 8;
        uint4 g = *(const uint4*)(ktbf + ((size_t)bn * CHD + d) * CL + l0 + cc);
        unsigned short* gp = (unsigned short*)&g;
        uint4 o;
        o.x = pk2(bf2f(gp[0]) * coefA[cc + 0], bf2f(gp[1]) * coefA[cc + 1]);
        o.y = pk2(bf2f(gp[2]) * coefA[cc + 2], bf2f(gp[3]) * coefA[cc + 3]);
        o.z = pk2(bf2f(gp[4]) * coefA[cc + 4], bf2f(gp[5]) * coefA[cc + 5]);
        o.w = pk2(bf2f(gp[6]) * coefA[cc + 6], bf2f(gp[7]) * coefA[cc + 7]);
        *(uint4*)&Ab[d][cc] = o;
    }
    __syncthreads();
    f32x4 acc[8];
#pragma unroll
    for (int i = 0; i < 8; ++i) acc[i] = (f32x4){0.f, 0.f, 0.f, 0.f};
#pragma unroll
    for (int h16 = 0; h16 < 8; ++h16)
#pragma unroll
        for (int ks = 0; ks < 2; ++ks) {
            short8v a = *(const short8v*)&Ab[wv * 16 + lm][ks * 32 + lg * 8];
            short8v b = *(const short8v*)&Bb[h16 * 16 + lm][ks * 32 + lg * 8];
            acc[h16] = MFMA16(a, b, acc[h16]);
        }
    float* og = (bn < 16 ? ds1 : ds2) + ((size_t)(((bn & 15) << 4) + c) << 13);
#pragma unroll
    for (int h16 = 0; h16 < 8; ++h16)
#pragma unroll
        for (int r = 0; r < 4; ++r)
            og[(wv * 16 + lg * 4 + r) * 128 + h16 * 16 + lm] = acc[h16][r];
}

// ---------------------------------------------------------------------------
// dsB1: state prefix scan + emit bf16 prefix states and w1n.
// Grid (8 element-groups, 32 bn): 8x parallelism over state elements.
// ---------------------------------------------------------------------------
__global__ __launch_bounds__(256) void dsB1(
    const float* __restrict__ ds1, const float* __restrict__ ds2,
    const float* __restrict__ cump, const float* __restrict__ W1,
    unsigned short* __restrict__ sp1, float* __restrict__ w1n) {
    __shared__ float anch[16];
    const int g = blockIdx.x, bn = blockIdx.y, t = threadIdx.x;
    if (t < 16) anch[t] = cump[(size_t)bn * CL + (t << 6)];
    __syncthreads();
    const float ccl = cump[(size_t)bn * CL + CL - 1];
    const float wdcl = __expf(ccl);
    const float* dS = (bn < 16 ? ds1 : ds2) + ((size_t)((bn & 15) << 4) << 13);
    unsigned short* spb = sp1 + ((size_t)bn << 17);
    const int e0 = g << 10;
    float s[4];
#pragma unroll
    for (int j = 0; j < 4; ++j) s[j] = 0.f;
    for (int c = 0; c < 16; ++c) {
        if (c > 0) {
            float fac = __expf(anch[c] - anch[c - 1]);
            const float* dp = dS + ((size_t)(c - 1) << 13);
#pragma unroll
            for (int j = 0; j < 4; ++j) s[j] = fac * (s[j] + dp[e0 + j * 256 + t]);
        }
        unsigned short* so = spb + ((size_t)c << 13);
#pragma unroll
        for (int j = 0; j < 4; ++j) so[e0 + j * 256 + t] = f2bf(s[j]);
    }
    const float ex = __expf(ccl - anch[15]);
    const float* dp = dS + ((size_t)15 << 13);
    const float* w1g = W1 + ((size_t)bn << 13);
    float* og = w1n + ((size_t)bn << 13);
#pragma unroll
    for (int j = 0; j < 4; ++j) {
        int e = e0 + j * 256 + t;
        int d = e >> 7, h = e & 127;
        float full = s[j] + dp[e];
        og[h * 64 + d] = wdcl * w1g[h * 64 + d] - ex * full;
    }
}

// ---------------------------------------------------------------------------
// dsC1: per-chunk layer-1 readout.
// ---------------------------------------------------------------------------
__global__ __launch_bounds__(256) void dsC1(
    const unsigned short* __restrict__ qbf, const unsigned short* __restrict__ kbf,
    const unsigned short* __restrict__ gz1t, const unsigned short* __restrict__ w1bf,
    const unsigned short* __restrict__ sp1, const float* __restrict__ lrp,
    const float* __restrict__ cump, const float* __restrict__ wdcp,
    unsigned short* __restrict__ x2q) {
    __shared__ __align__(16) unsigned short Qb[64][72];
    __shared__ __align__(16) unsigned short XB[128][72];
    __shared__ __align__(16) unsigned short Kb[64][72];
    __shared__ __align__(16) unsigned short GT[128][72];
    __shared__ __align__(16) unsigned short Pm[64][72];
    __shared__ float lrc[64], cumc[64], wdcc[64];
    const int c = blockIdx.x, bn = blockIdx.y, t = threadIdx.x;
    const int l0 = c << 6;
    const int w4 = t >> 6, lane = t & 63;
    const int lm = lane & 15, lg = lane >> 4;
    {
        const unsigned short* qg = qbf + ((size_t)bn * CL + l0) * CHD;
        for (int i = t; i < 512; i += 256) {
            int r = i >> 3, cc = (i & 7) * 8;
            *(uint4*)&Qb[r][cc] = *(const uint4*)(qg + (size_t)r * CHD + cc);
        }
        const unsigned short* wg = w1bf + (size_t)bn * CHDH * CHD;
        for (int i = t; i < 1024; i += 256) {
            int r = i >> 3, cc = (i & 7) * 8;
            *(uint4*)&XB[r][cc] = *(const uint4*)(wg + (size_t)r * CHD + cc);
        }
        if (t < 64) {
            lrc[t] = lrp[(size_t)bn * CL + l0 + t];
            cumc[t] = cump[(size_t)bn * CL + l0 + t];
            wdcc[t] = wdcp[(size_t)bn * CL + l0 + t];
        }
    }
    __syncthreads();
    const float Ac = cumc[0];
    short8v qf[4][2];
#pragma unroll
    for (int m16 = 0; m16 < 4; ++m16)
#pragma unroll
        for (int ks = 0; ks < 2; ++ks)
            qf[m16][ks] = *(const short8v*)&Qb[m16 * 16 + lm][ks * 32 + lg * 8];
    f32x4 acc[4][2];
#pragma unroll
    for (int i = 0; i < 4; ++i)
#pragma unroll
        for (int j = 0; j < 2; ++j) acc[i][j] = (f32x4){0.f, 0.f, 0.f, 0.f};
    {
        short8v wf[2][2];
#pragma unroll
        for (int hh = 0; hh < 2; ++hh)
#pragma unroll
            for (int ks = 0; ks < 2; ++ks)
                wf[hh][ks] =
                    *(const short8v*)&XB[(w4 * 2 + hh) * 16 + lm][ks * 32 + lg * 8];
#pragma unroll
        for (int m16 = 0; m16 < 4; ++m16)
#pragma unroll
            for (int hh = 0; hh < 2; ++hh)
#pragma unroll
                for (int ks = 0; ks < 2; ++ks)
                    acc[m16][hh] = MFMA16(qf[m16][ks], wf[hh][ks], acc[m16][hh]);
#pragma unroll
        for (int m16 = 0; m16 < 4; ++m16)
#pragma unroll
            for (int r = 0; r < 4; ++r) {
                float w = wdcc[m16 * 16 + lg * 4 + r];
                acc[m16][0][r] *= w;
                acc[m16][1][r] *= w;
            }
    }
    __syncthreads();
    {
        const unsigned short* sb = sp1 + ((((size_t)bn << 4) + c) << 13);
        for (int i = t; i < 1024; i += 256) {
            int d = i >> 4, hg = (i & 15) * 8;
            uint4 u = *(const uint4*)(sb + d * 128 + hg);
            const unsigned short* up = (const unsigned short*)&u;
#pragma unroll
            for (int j = 0; j < 8; ++j) XB[hg + j][d] = up[j];
        }
    }
    __syncthreads();
    {
        short8v sf[2][2];
#pragma unroll
        for (int hh = 0; hh < 2; ++hh)
#pragma unroll
            for (int ks = 0; ks < 2; ++ks)
                sf[hh][ks] =
                    *(const short8v*)&XB[(w4 * 2 + hh) * 16 + lm][ks * 32 + lg * 8];
#pragma unroll
        for (int m16 = 0; m16 < 4; ++m16)
#pragma unroll
            for (int hh = 0; hh < 2; ++hh) {
                f32x4 pf = (f32x4){0.f, 0.f, 0.f, 0.f};
#pragma unroll
                for (int ks = 0; ks < 2; ++ks)
                    pf = MFMA16(qf[m16][ks], sf[hh][ks], pf);
#pragma unroll
                for (int r = 0; r < 4; ++r) {
                    float em = __expf(cumc[m16 * 16 + lg * 4 + r] - Ac);
                    acc[m16][hh][r] -= em * pf[r];
                }
            }
    }
    __syncthreads();
    {
        const unsigned short* kg = kbf + ((size_t)bn * CL + l0) * CHD;
        for (int i = t; i < 512; i += 256) {
            int r = i >> 3, cc = (i & 7) * 8;
            *(uint4*)&Kb[r][cc] = *(const uint4*)(kg + (size_t)r * CHD + cc);
        }
        const unsigned short* gg = gz1t + (size_t)bn * CHDH * CL + l0;
        for (int i = t; i < 1024; i += 256) {
            int r = i >> 3, cc = (i & 7) * 8;
            *(uint4*)&GT[r][cc] = *(const uint4*)(gg + (size_t)r * CL + cc);
        }
    }
    __syncthreads();
    {
        short8v kf[2];
#pragma unroll
        for (int ks = 0; ks < 2; ++ks)
            kf[ks] = *(const short8v*)&Kb[w4 * 16 + lm][ks * 32 + lg * 8];
#pragma unroll
        for (int m16 = 0; m16 < 4; ++m16) {
            f32x4 s = (f32x4){0.f, 0.f, 0.f, 0.f};
#pragma unroll
            for (int ks = 0; ks < 2; ++ks) s = MFMA16(kf[ks], qf[m16][ks], s);
            int mloc = m16 * 16 + lm;
            float cm = cumc[mloc];
            unsigned short pv[4];
#pragma unroll
            for (int r = 0; r < 4; ++r) {
                int lloc = w4 * 16 + lg * 4 + r;
                float val = (mloc >= lloc)
                                ? s[r] * lrc[lloc] * __expf(cm - cumc[lloc])
                                : 0.f;
                pv[r] = f2bf(val);
            }
            *(uint2*)&Pm[mloc][w4 * 16 + lg * 4] =
                make_uint2(pkus(pv[0], pv[1]), pkus(pv[2], pv[3]));
        }
    }
    __syncthreads();
    {
        short8v gt[2][2], pm[4][2];
#pragma unroll
        for (int hh = 0; hh < 2; ++hh)
#pragma unroll
            for (int ks = 0; ks < 2; ++ks)
                gt[hh][ks] =
                    *(const short8v*)&GT[(w4 * 2 + hh) * 16 + lm][ks * 32 + lg * 8];
#pragma unroll
        for (int m16 = 0; m16 < 4; ++m16)
#pragma unroll
            for (int ks = 0; ks < 2; ++ks)
                pm[m16][ks] = *(const short8v*)&Pm[m16 * 16 + lm][ks * 32 + lg * 8];
#pragma unroll
        for (int m16 = 0; m16 < 4; ++m16)
#pragma unroll
            for (int hh = 0; hh < 2; ++hh) {
                f32x4 pf = (f32x4){0.f, 0.f, 0.f, 0.f};
#pragma unroll
                for (int ks = 0; ks < 2; ++ks) pf = MFMA16(pm[m16][ks], gt[hh][ks], pf);
#pragma unroll
                for (int r = 0; r < 4; ++r) acc[m16][hh][r] -= pf[r];
            }
    }
    __syncthreads();
    {
        unsigned short(*Ob)[136] = (unsigned short(*)[136])XB;
#pragma unroll
        for (int m16 = 0; m16 < 4; ++m16)
#pragma unroll
            for (int hh = 0; hh < 2; ++hh) {
                int h = (w4 * 2 + hh) * 16 + lm;
#pragma unroll
                for (int r = 0; r < 4; ++r) {
                    float a = acc[m16][hh][r];
                    Ob[m16 * 16 + lg * 4 + r][h] = f2bf(a * sigf(a));
                }
            }
        __syncthreads();
        unsigned short* og = x2q + ((size_t)bn * CL + l0) * CHDH;
        for (int i = t; i < 1024; i += 256) {
            int r = i >> 4, cc = (i & 15) * 8;
            *(uint4*)(og + (size_t)r * CHDH + cc) = *(const uint4*)&Ob[r][cc];
        }
    }
}

// ---------------------------------------------------------------------------
// dsA2: per-chunk state delta for layer 2.
// ---------------------------------------------------------------------------
__global__ __launch_bounds__(256) void dsA2(
    const unsigned short* __restrict__ x2t, const unsigned short* __restrict__ gz2t,
    const float* __restrict__ lrp, const float* __restrict__ cump,
    float* __restrict__ ds1, float* __restrict__ ds2) {
    __shared__ __align__(16) unsigned short Ab[128][72];
    __shared__ __align__(16) unsigned short Bb[64][72];
    __shared__ float coefA[64];
    const int c = blockIdx.x, bn = blockIdx.y, t = threadIdx.x;
    const int l0 = c << 6;
    const int wv = t >> 6, lane = t & 63;
    const int lm = lane & 15, lg = lane >> 4;
    const float Ac = cump[(size_t)bn * CL + l0];
    if (t < 64)
        coefA[t] = lrp[(size_t)bn * CL + l0 + t] *
                   __expf(Ac - cump[(size_t)bn * CL + l0 + t]);
    for (int i = t; i < 512; i += 256) {
        int d = i >> 3, cc = (i & 7) * 8;
        *(uint4*)&Bb[d][cc] = *(const uint4*)(gz2t + ((size_t)bn * CHD + d) * CL + l0 + cc);
    }
    __syncthreads();
    for (int i = t; i < 1024; i += 256) {
        int h = i >> 3, cc = (i & 7) * 8;
        uint4 g = *(const uint4*)(x2t + ((size_t)bn * CHDH + h) * CL + l0 + cc);
        unsigned short* gp = (unsigned short*)&g;
        uint4 o;
        o.x = pk2(bf2f(gp[0]) * coefA[cc + 0], bf2f(gp[1]) * coefA[cc + 1]);
        o.y = pk2(bf2f(gp[2]) * coefA[cc + 2], bf2f(gp[3]) * coefA[cc + 3]);
        o.z = pk2(bf2f(gp[4]) * coefA[cc + 4], bf2f(gp[5]) * coefA[cc + 5]);
        o.w = pk2(bf2f(gp[6]) * coefA[cc + 6], bf2f(gp[7]) * coefA[cc + 7]);
        *(uint4*)&Ab[h][cc] = o;
    }
    __syncthreads();
    f32x4 acc[2][4];
#pragma unroll
    for (int i = 0; i < 2; ++i)
#pragma unroll
        for (int j = 0; j < 4; ++j) acc[i][j] = (f32x4){0.f, 0.f, 0.f, 0.f};
#pragma unroll
    for (int mm = 0; mm < 2; ++mm) {
        int hk16 = wv * 2 + mm;
#pragma unroll
        for (int d16 = 0; d16 < 4; ++d16)
#pragma unroll
            for (int ks = 0; ks < 2; ++ks) {
                short8v a = *(const short8v*)&Ab[hk16 * 16 + lm][ks * 32 + lg * 8];
                short8v b = *(const short8v*)&Bb[d16 * 16 + lm][ks * 32 + lg * 8];
                acc[mm][d16] = MFMA16(a, b, acc[mm][d16]);
            }
    }
    float* og = (bn < 16 ? ds1 : ds2) + ((size_t)(((bn & 15) << 4) + c) << 13);
#pragma unroll
    for (int mm = 0; mm < 2; ++mm)
#pragma unroll
        for (int d16 = 0; d16 < 4; ++d16)
#pragma unroll
            for (int r = 0; r < 4; ++r)
                og[((wv * 2 + mm) * 16 + lg * 4 + r) * 64 + d16 * 16 + lm] =
                    acc[mm][d16][r];
}

// ---------------------------------------------------------------------------
// dsB2: scan for layer 2 + w2n. Grid (8 element-groups, 32 bn).
// ---------------------------------------------------------------------------
__global__ __launch_bounds__(256) void dsB2(
    const float* __restrict__ ds1, const float* __restrict__ ds2,
    const float* __restrict__ cump, const float* __restrict__ W2,
    unsigned short* __restrict__ sp2, float* __restrict__ w2n) {
    __shared__ float anch[16];
    const int g = blockIdx.x, bn = blockIdx.y, t = threadIdx.x;
    if (t < 16) anch[t] = cump[(size_t)bn * CL + (t << 6)];
    __syncthreads();
    const float ccl = cump[(size_t)bn * CL + CL - 1];
    const float wdcl = __expf(ccl);
    const float* dS = (bn < 16 ? ds1 : ds2) + ((size_t)((bn & 15) << 4) << 13);
    unsigned short* spb = sp2 + ((size_t)bn << 17);
    const int e0 = g << 10;
    float s[4];
#pragma unroll
    for (int j = 0; j < 4; ++j) s[j] = 0.f;
    for (int c = 0; c < 16; ++c) {
        if (c > 0) {
            float fac = __expf(anch[c] - anch[c - 1]);
            const float* dp = dS + ((size_t)(c - 1) << 13);
#pragma unroll
            for (int j = 0; j < 4; ++j) s[j] = fac * (s[j] + dp[e0 + j * 256 + t]);
        }
        unsigned short* so = spb + ((size_t)c << 13);
#pragma unroll
        for (int j = 0; j < 4; ++j) so[e0 + j * 256 + t] = f2bf(s[j]);
    }
    const float ex = __expf(ccl - anch[15]);
    const float* dp = dS + ((size_t)15 << 13);
    const float* w2g = W2 + ((size_t)bn << 13);
    float* og = w2n + ((size_t)bn << 13);
#pragma unroll
    for (int j = 0; j < 4; ++j) {
        int e = e0 + j * 256 + t;
        int hk = e >> 6, d = e & 63;
        float full = s[j] + dp[e];
        og[d * 128 + hk] = wdcl * w2g[d * 128 + hk] - ex * full;
    }
}

// ---------------------------------------------------------------------------
// dsC2: per-chunk layer-2 readout. Emits z2s as pre-split hi/lo bf16.
// ---------------------------------------------------------------------------
__global__ __launch_bounds__(256) void dsC2(
    const unsigned short* __restrict__ x2q, const unsigned short* __restrict__ x2bf,
    const unsigned short* __restrict__ gz2t, const unsigned short* __restrict__ w2bf,
    const unsigned short* __restrict__ sp2, const float* __restrict__ lrp,
    const float* __restrict__ cump, const float* __restrict__ wdcp,
    unsigned short* __restrict__ zh, unsigned short* __restrict__ zl) {
    __shared__ __align__(16) unsigned short X2qb[64][136];
    __shared__ __align__(16) unsigned short XB[64][136];
    __shared__ __align__(16) unsigned short GT2[64][72];
    __shared__ __align__(16) unsigned short Pm[64][72];
    __shared__ float lrc[64], cumc[64], wdcc[64];
    const int c = blockIdx.x, bn = blockIdx.y, t = threadIdx.x;
    const int l0 = c << 6;
    const int w4 = t >> 6, lane = t & 63;
    const int lm = lane & 15, lg = lane >> 4;
    {
        const unsigned short* qg = x2q + ((size_t)bn * CL + l0) * CHDH;
        for (int i = t; i < 1024; i += 256) {
            int r = i >> 4, cc = (i & 15) * 8;
            *(uint4*)&X2qb[r][cc] = *(const uint4*)(qg + (size_t)r * CHDH + cc);
        }
        const unsigned short* wg = w2bf + (size_t)bn * CHD * CHDH;
        for (int i = t; i < 1024; i += 256) {
            int r = i >> 4, cc = (i & 15) * 8;
            *(uint4*)&XB[r][cc] = *(const uint4*)(wg + (size_t)r * CHDH + cc);
        }
        if (t < 64) {
            lrc[t] = lrp[(size_t)bn * CL + l0 + t];
            cumc[t] = cump[(size_t)bn * CL + l0 + t];
            wdcc[t] = wdcp[(size_t)bn * CL + l0 + t];
        }
    }
    __syncthreads();
    const float Ac = cumc[0];
    short8v qf[4][4];
#pragma unroll
    for (int m16 = 0; m16 < 4; ++m16)
#pragma unroll
        for (int ks = 0; ks < 4; ++ks)
            qf[m16][ks] = *(const short8v*)&X2qb[m16 * 16 + lm][ks * 32 + lg * 8];
    f32x4 acc[4];
#pragma unroll
    for (int i = 0; i < 4; ++i) acc[i] = (f32x4){0.f, 0.f, 0.f, 0.f};
    {
        short8v wf[4];
#pragma unroll
        for (int ks = 0; ks < 4; ++ks)
            wf[ks] = *(const short8v*)&XB[w4 * 16 + lm][ks * 32 + lg * 8];
#pragma unroll
        for (int m16 = 0; m16 < 4; ++m16)
#pragma unroll
            for (int ks = 0; ks < 4; ++ks)
                acc[m16] = MFMA16(qf[m16][ks], wf[ks], acc[m16]);
#pragma unroll
        for (int m16 = 0; m16 < 4; ++m16)
#pragma unroll
            for (int r = 0; r < 4; ++r)
                acc[m16][r] *= wdcc[m16 * 16 + lg * 4 + r];
    }
    __syncthreads();
    {
        const unsigned short* sb = sp2 + ((((size_t)bn << 4) + c) << 13);
        for (int i = t; i < 1024; i += 256) {
            int hk = i >> 3, dg = (i & 7) * 8;
            uint4 u = *(const uint4*)(sb + hk * 64 + dg);
            const unsigned short* up = (const unsigned short*)&u;
#pragma unroll
            for (int j = 0; j < 8; ++j) XB[dg + j][hk] = up[j];
        }
    }
    __syncthreads();
    {
        short8v sf[4];
#pragma unroll
        for (int ks = 0; ks < 4; ++ks)
            sf[ks] = *(const short8v*)&XB[w4 * 16 + lm][ks * 32 + lg * 8];
#pragma unroll
        for (int m16 = 0; m16 < 4; ++m16) {
            f32x4 pf = (f32x4){0.f, 0.f, 0.f, 0.f};
#pragma unroll
            for (int ks = 0; ks < 4; ++ks) pf = MFMA16(qf[m16][ks], sf[ks], pf);
#pragma unroll
            for (int r = 0; r < 4; ++r) {
                float em = __expf(cumc[m16 * 16 + lg * 4 + r] - Ac);
                acc[m16][r] -= em * pf[r];
            }
        }
    }
    __syncthreads();
    {
        const unsigned short* kg = x2bf + ((size_t)bn * CL + l0) * CHDH;
        for (int i = t; i < 1024; i += 256) {
            int r = i >> 4, cc = (i & 15) * 8;
            *(uint4*)&XB[r][cc] = *(const uint4*)(kg + (size_t)r * CHDH + cc);
        }
        const unsigned short* gg = gz2t + (size_t)bn * CHD * CL + l0;
        for (int i = t; i < 512; i += 256) {
            int r = i >> 3, cc = (i & 7) * 8;
            *(uint4*)&GT2[r][cc] = *(const uint4*)(gg + (size_t)r * CL + cc);
        }
    }
    __syncthreads();
    {
        short8v kf[4];
#pragma unroll
        for (int ks = 0; ks < 4; ++ks)
            kf[ks] = *(const short8v*)&XB[w4 * 16 + lm][ks * 32 + lg * 8];
#pragma unroll
        for (int m16 = 0; m16 < 4; ++m16) {
            f32x4 s = (f32x4){0.f, 0.f, 0.f, 0.f};
#pragma unroll
            for (int ks = 0; ks < 4; ++ks) s = MFMA16(kf[ks], qf[m16][ks], s);
            int mloc = m16 * 16 + lm;
            float cm = cumc[mloc];
            unsigned short pv[4];
#pragma unroll
            for (int r = 0; r < 4; ++r) {
                int lloc = w4 * 16 + lg * 4 + r;
                float val = (mloc >= lloc)
                                ? s[r] * lrc[lloc] * __expf(cm - cumc[lloc])
                                : 0.f;
                pv[r] = f2bf(val);
            }
            *(uint2*)&Pm[mloc][w4 * 16 + lg * 4] =
                make_uint2(pkus(pv[0], pv[1]), pkus(pv[2], pv[3]));
        }
    }
    __syncthreads();
    {
        short8v gt[2], pm[4][2];
#pragma unroll
        for (int ks = 0; ks < 2; ++ks)
            gt[ks] = *(const short8v*)&GT2[w4 * 16 + lm][ks * 32 + lg * 8];
#pragma unroll
        for (int m16 = 0; m16 < 4; ++m16)
#pragma unroll
            for (int ks = 0; ks < 2; ++ks)
                pm[m16][ks] = *(const short8v*)&Pm[m16 * 16 + lm][ks * 32 + lg * 8];
#pragma unroll
        for (int m16 = 0; m16 < 4; ++m16) {
            f32x4 pf = (f32x4){0.f, 0.f, 0.f, 0.f};
#pragma unroll
            for (int ks = 0; ks < 2; ++ks) pf = MFMA16(pm[m16][ks], gt[ks], pf);
#pragma unroll
            for (int r = 0; r < 4; ++r) acc[m16][r] -= pf[r];
        }
    }
    __syncthreads();
    {  // store pre-split hi/lo bf16 via fp32 LDS bounce
        float(*Os)[68] = (float(*)[68])X2qb;
#pragma unroll
        for (int m16 = 0; m16 < 4; ++m16)
#pragma unroll
            for (int r = 0; r < 4; ++r)
                Os[m16 * 16 + lg * 4 + r][w4 * 16 + lm] = acc[m16][r];
        __syncthreads();
        unsigned short* zhg = zh + ((size_t)bn * CL + l0) * CHD;
        unsigned short* zlg = zl + ((size_t)bn * CL + l0) * CHD;
        for (int i = t; i < 1024; i += 256) {
            int r = i >> 4, cc = (i & 15) << 2;
            float4 v = *(const float4*)&Os[r][cc];
            unsigned short h0 = f2bf(v.x), h1 = f2bf(v.y), h2 = f2bf(v.z), h3 = f2bf(v.w);
            *(uint2*)(zhg + (size_t)r * CHD + cc) = make_uint2(pkus(h0, h1), pkus(h2, h3));
            *(uint2*)(zlg + (size_t)r * CHD + cc) = make_uint2(
                pk2(v.x - bf2f(h0), v.y - bf2f(h1)), pk2(v.z - bf2f(h2), v.w - bf2f(h3)));
        }
    }
}

// ---------------------------------------------------------------------------
extern "C" void kernel_launch(void* const* d_in, const int* in_sizes, int n_in,
                              void* d_out, int out_size, void* d_ws, size_t ws_size,
                              hipStream_t stream) {
    (void)in_sizes; (void)n_in; (void)out_size; (void)ws_size;
    const float* x      = (const float*)d_in[0];
    const float* W1     = (const float*)d_in[1];
    const float* W2     = (const float*)d_in[2];
    const float* lblr   = (const float*)d_in[3];
    const float* fclr_w = (const float*)d_in[4];
    const float* fclr_b = (const float*)d_in[5];
    const float* lbwd   = (const float*)d_in[6];
    const float* fcwd_w = (const float*)d_in[7];
    const float* fcwd_b = (const float*)d_in[8];
    const float* qw = (const float*)d_in[9];
    const float* qb = (const float*)d_in[10];
    const float* kw = (const float*)d_in[11];
    const float* kb = (const float*)d_in[12];
    const float* vw = (const float*)d_in[13];
    const float* vb = (const float*)d_in[14];
    const float* ow = (const float*)d_in[15];
    const float* ob = (const float*)d_in[16];

    float* ws = (float*)d_ws;
    const size_t SZ_HD = (size_t)CBN * CL * CHD;
    const size_t SZ_HDH = (size_t)CBN * CL * CHDH;
    float* qh   = ws;
    float* khb  = qh + SZ_HD;
    float* vhb  = khb + SZ_HD;
    float* gz2b = vhb + SZ_HD;
    float* z2sb = gz2b + SZ_HD;
    float* x2b  = z2sb + SZ_HD;
    float* gz1b = x2b + SZ_HDH;
    float* x2qb = gz1b + SZ_HDH;
    float* lrb  = x2qb + SZ_HDH;
    float* cumb = lrb + (size_t)CBN * CL;
    float* wdcb = cumb + (size_t)CBN * CL;
    unsigned short* xbf  = (unsigned short*)(wdcb + (size_t)CBN * CL);
    unsigned short* qwbf = xbf + (size_t)CB * CL * CD;
    unsigned short* kwbf = qwbf + (size_t)CD * CD;
    unsigned short* vwbf = kwbf + (size_t)CD * CD;
    unsigned short* owh  = vwbf + (size_t)CD * CD;
    unsigned short* owl  = owh + (size_t)CD * CD;

    unsigned short* qbf   = (unsigned short*)qh;
    unsigned short* kbf   = qbf + SZ_HD;
    unsigned short* ktbf  = (unsigned short*)khb;
    unsigned short* w1bf  = ktbf + SZ_HD;
    unsigned short* w2bf  = w1bf + (size_t)CBN * CHDH * CHD;
    unsigned short* w2tbf = w2bf + (size_t)CBN * CHDH * CHD;
    unsigned short* gz2t  = (unsigned short*)gz2b;
    unsigned short* x2t   = (unsigned short*)x2b;
    unsigned short* gz1t  = (unsigned short*)gz1b;
    unsigned short* x2q   = (unsigned short*)x2qb;
    unsigned short* x2bf  = x2q + SZ_HDH;
    float* ds1 = gz1b + 2097152;
    float* ds2 = x2b + 2097152;
    unsigned short* sp1 = (unsigned short*)vhb;
    unsigned short* sp2 = (unsigned short*)vhb;
    unsigned short* zh = (unsigned short*)z2sb;  // z2s hi bf16 (4 MB)
    unsigned short* zl = zh + SZ_HD;             // z2s lo bf16 (4 MB)

    float* outp = (float*)d_out;
    float* w1n = outp + (size_t)CB * CL * CD;
    float* w2n = w1n + (size_t)CBN * CHDH * CHD;

    conv_kernel<<<6912, 256, 0, stream>>>(x, qw, kw, vw, W1, W2, ow, xbf, qwbf, kwbf,
                                          vwbf, w1bf, w2bf, w2tbf, owh, owl);
    qkv_mfma<<<dim3(24, 32), 512, 0, stream>>>(xbf, qwbf, qb, kb, vb, qbf, kbf, ktbf,
                                               vhb);
    lrwd_kernel<<<CB * CL, 64, 0, stream>>>(x, lblr, fclr_w, fclr_b, lbwd, fcwd_w,
                                            fcwd_b, lrb, cumb);
    scan_kernel<<<CBN, 64, 0, stream>>>(cumb, wdcb);
    mlp_mfma<<<dim3(CL / 64, CBN), 256, 0, stream>>>(kbf, vhb, w1bf, w2bf, w2tbf,
                                                     x2bf, x2t, gz1t, gz2t);
    dsA1<<<dim3(16, CBN), 256, 0, stream>>>(ktbf, gz1t, lrb, cumb, ds1, ds2);
    dsB1<<<dim3(8, CBN), 256, 0, stream>>>(ds1, ds2, cumb, W1, sp1, w1n);
    dsC1<<<dim3(16, CBN), 256, 0, stream>>>(qbf, kbf, gz1t, w1bf, sp1, lrb, cumb,
                                            wdcb, x2q);
    dsA2<<<dim3(16, CBN), 256, 0, stream>>>(x2t, gz2t, lrb, cumb, ds1, ds2);
    dsB2<<<dim3(8, CBN), 256, 0, stream>>>(ds1, ds2, cumb, W2, sp2, w2n);
    dsC2<<<dim3(16, CBN), 256, 0, stream>>>(x2q, x2bf, gz2t, w2bf, sp2, lrb, cumb,
                                            wdcb, zh, zl);
    gemm_obf<<<dim3(32, 8), 512, 0, stream>>>(zh, zl, owh, owl, ob, outp);
}

// Round 20
// 168.114 us; speedup vs baseline: 1.0610x; 1.0610x over previous
//
#include <hip/hip_runtime.h>

constexpr int CB = 2, CL = 1024, CD = 1024, CNH = 16, CHD = 64, CHDH = 128, CBN = CB * CNH;

__device__ __forceinline__ float sigf(float x) { return 1.0f / (1.0f + __expf(-x)); }

__device__ __forceinline__ unsigned short f2bf(float x) {
    unsigned u = __float_as_uint(x);
    u += 0x7fffu + ((u >> 16) & 1u);
    return (unsigned short)(u >> 16);
}
__device__ __forceinline__ unsigned pk2(float a, float b) {
    return (unsigned)f2bf(a) | ((unsigned)f2bf(b) << 16);
}
__device__ __forceinline__ unsigned pkus(unsigned short a, unsigned short b) {
    return (unsigned)a | ((unsigned)b << 16);
}
__device__ __forceinline__ float bf2f(unsigned short u) {
    return __uint_as_float(((unsigned)u) << 16);
}

typedef __attribute__((ext_vector_type(8))) short short8v;
typedef __attribute__((ext_vector_type(4))) float f32x4;
#define MFMA16(a, b, c) __builtin_amdgcn_mfma_f32_16x16x32_bf16(a, b, c, 0, 0, 0)

// ---------------------------------------------------------------------------
// Merged conversions.
// ---------------------------------------------------------------------------
__global__ __launch_bounds__(256) void conv_kernel(
    const float* __restrict__ x, const float* __restrict__ qw,
    const float* __restrict__ kw, const float* __restrict__ vw,
    const float* __restrict__ W1, const float* __restrict__ W2,
    const float* __restrict__ ow, unsigned short* __restrict__ xb,
    unsigned short* __restrict__ qwb, unsigned short* __restrict__ kwb,
    unsigned short* __restrict__ vwb, unsigned short* __restrict__ w1b,
    unsigned short* __restrict__ w2b, unsigned short* __restrict__ w2t,
    unsigned short* __restrict__ owh, unsigned short* __restrict__ owl) {
    int i = blockIdx.x * 256 + threadIdx.x;
    if (i < 1310720) {
        const float* s;
        unsigned short* d;
        int off;
        if (i < 524288) { s = x; d = xb; off = i; }
        else if (i < 786432) { s = qw; d = qwb; off = i - 524288; }
        else if (i < 1048576) { s = kw; d = kwb; off = i - 786432; }
        else { s = vw; d = vwb; off = i - 1048576; }
        float4 v = *(const float4*)(s + (size_t)off * 4);
        *(uint2*)(d + (size_t)off * 4) = make_uint2(pk2(v.x, v.y), pk2(v.z, v.w));
    } else if (i < 1507328) {
        int j = i - 1310720;
        if (j < 65536) {
            size_t e = (size_t)j * 4;
            float4 v = *(const float4*)(W1 + e);
            *(uint2*)(w1b + e) = make_uint2(pk2(v.x, v.y), pk2(v.z, v.w));
        } else if (j < 131072) {
            size_t e = (size_t)(j - 65536) * 4;
            float4 v = *(const float4*)(W2 + e);
            *(uint2*)(w2b + e) = make_uint2(pk2(v.x, v.y), pk2(v.z, v.w));
        } else {
            size_t e = (size_t)(j - 131072) * 4;
            int bn = (int)(e >> 13), rem = (int)(e & 8191);
            int h = rem >> 6, d0 = rem & 63;
            const float* src = W2 + (size_t)bn * CHD * CHDH;
            float a = src[(d0 + 0) * CHDH + h], b = src[(d0 + 1) * CHDH + h];
            float c = src[(d0 + 2) * CHDH + h], dd = src[(d0 + 3) * CHDH + h];
            *(uint2*)(w2t + e) = make_uint2(pk2(a, b), pk2(c, dd));
        }
    } else {
        size_t e = (size_t)(i - 1507328) * 4;
        float4 v = *(const float4*)(ow + e);
        unsigned short h0 = f2bf(v.x), h1 = f2bf(v.y), h2 = f2bf(v.z), h3 = f2bf(v.w);
        *(uint2*)(owh + e) = make_uint2(pkus(h0, h1), pkus(h2, h3));
        *(uint2*)(owl + e) = make_uint2(
            pk2(v.x - bf2f(h0), v.y - bf2f(h1)), pk2(v.z - bf2f(h2), v.w - bf2f(h3)));
    }
}

// ---------------------------------------------------------------------------
// Merged q/k/v projection GEMM: 64x128 tile, BK=128 (8 K-iterations).
// Grid (24 col-tiles, 32 row-tiles) = 768 blocks.
// ---------------------------------------------------------------------------
__global__ __launch_bounds__(512) void qkv_mfma(
    const unsigned short* __restrict__ xbf, const unsigned short* __restrict__ wqkv,
    const float* __restrict__ qb, const float* __restrict__ kb,
    const float* __restrict__ vb, unsigned short* __restrict__ qbf,
    unsigned short* __restrict__ kbf, unsigned short* __restrict__ ktbf,
    float* __restrict__ vhb) {
    __shared__ __align__(16) unsigned short SM[26112];  // 52224 B
    unsigned short(*Ab)[136] = (unsigned short(*)[136])SM;           // [64][136]
    unsigned short(*Bb)[136] = (unsigned short(*)[136])(SM + 8704);  // [128][136]
    const int t = threadIdx.x;
    const int c0 = blockIdx.x << 7, r0 = blockIdx.y << 6;
    const int wv = t >> 6, lane = t & 63;
    const int lm = lane & 15, lg = lane >> 4;
    f32x4 acc[4];
#pragma unroll
    for (int i = 0; i < 4; ++i) acc[i] = (f32x4){0.f, 0.f, 0.f, 0.f};
    for (int kc = 0; kc < CD; kc += 128) {
        for (int i = t; i < 1024; i += 512) {
            int r = i >> 4, c = (i & 15) * 8;
            *(uint4*)&Ab[r][c] = *(const uint4*)(xbf + (size_t)(r0 + r) * CD + kc + c);
        }
        for (int i = t; i < 2048; i += 512) {
            int r = i >> 4, c = (i & 15) * 8;
            *(uint4*)&Bb[r][c] = *(const uint4*)(wqkv + (size_t)(c0 + r) * CD + kc + c);
        }
        __syncthreads();
#pragma unroll
        for (int m16 = 0; m16 < 4; ++m16)
#pragma unroll
            for (int ks = 0; ks < 4; ++ks) {
                short8v a = *(const short8v*)&Ab[m16 * 16 + lm][ks * 32 + lg * 8];
                short8v b = *(const short8v*)&Bb[wv * 16 + lm][ks * 32 + lg * 8];
                acc[m16] = MFMA16(a, b, acc[m16]);
            }
        __syncthreads();
    }
    const int which = c0 >> 10;
    const int ccb = c0 & 1023;
    const float* bias = which == 0 ? qb : (which == 1 ? kb : vb);
    const int b = r0 >> 10, lb0 = r0 & 1023;
    float(*Os)[132] = (float(*)[132])SM;  // 64x132 f32 = 33792 B overlay
    {
        int col = wv * 16 + lm;
        float bb = bias[ccb + col];
#pragma unroll
        for (int m16 = 0; m16 < 4; ++m16)
#pragma unroll
            for (int r = 0; r < 4; ++r)
                Os[m16 * 16 + lg * 4 + r][col] = acc[m16][r] + bb;
    }
    __syncthreads();
    if (which == 2) {
        for (int i = t; i < 2048; i += 512) {
            int r = i >> 5, c = (i & 31) * 4;
            int n = (ccb + c) >> 6, d = (ccb + c) & 63;
            *(float4*)(vhb + (((size_t)b * CNH + n) * CL + lb0 + r) * 64 + d) =
                *(const float4*)&Os[r][c];
        }
    } else {
        unsigned short* dst = which == 0 ? qbf : kbf;
        for (int i = t; i < 2048; i += 512) {
            int r = i >> 5, c = (i & 31) * 4;
            int n = (ccb + c) >> 6, d = (ccb + c) & 63;
            float4 v4 = *(const float4*)&Os[r][c];
            *(uint2*)(dst + (((size_t)b * CNH + n) * CL + lb0 + r) * 64 + d) =
                make_uint2(pk2(v4.x, v4.y), pk2(v4.z, v4.w));
        }
        if (which == 1) {
            for (int i = t; i < 1024; i += 512) {
                int col = i >> 3, lb = (i & 7) * 8;
                int n = (ccb + col) >> 6, d = (ccb + col) & 63;
                uint4 u;
                u.x = pk2(Os[lb + 0][col], Os[lb + 1][col]);
                u.y = pk2(Os[lb + 2][col], Os[lb + 3][col]);
                u.z = pk2(Os[lb + 4][col], Os[lb + 5][col]);
                u.w = pk2(Os[lb + 6][col], Os[lb + 7][col]);
                *(uint4*)(ktbf + (((size_t)b * CNH + n) * 64 + d) * CL + lb0 + lb) = u;
            }
        }
    }
}

// ---------------------------------------------------------------------------
// Split-precision MFMA o-projection: BK=128 (8 K-iterations), 104 KB LDS.
// Grid (32 rows, 8 cols): blocks sharing a row-panel land on one XCD.
// ---------------------------------------------------------------------------
__global__ __launch_bounds__(512) void gemm_obf(const unsigned short* __restrict__ zh,
                                                const unsigned short* __restrict__ zl,
                                                const unsigned short* __restrict__ Bh,
                                                const unsigned short* __restrict__ Bl,
                                                const float* __restrict__ bias,
                                                float* __restrict__ C) {
    __shared__ __align__(16) unsigned short SM[52224];  // 104448 B
    unsigned short(*Ah)[136] = (unsigned short(*)[136])SM;             // [64][136]
    unsigned short(*Al)[136] = (unsigned short(*)[136])(SM + 8704);    // [64][136]
    unsigned short(*Bhs)[136] = (unsigned short(*)[136])(SM + 17408);  // [128][136]
    unsigned short(*Bls)[136] = (unsigned short(*)[136])(SM + 34816);  // [128][136]
    const int t = threadIdx.x;
    const int r0 = blockIdx.x << 6, c0 = blockIdx.y << 7;
    const int wv = t >> 6, lane = t & 63;
    const int lm = lane & 15, lg = lane >> 4;
    const int b = r0 >> 10, lb0 = r0 & 1023;
    f32x4 acc[4];
#pragma unroll
    for (int i = 0; i < 4; ++i) acc[i] = (f32x4){0.f, 0.f, 0.f, 0.f};
    for (int kc = 0; kc < CD; kc += 128) {
        for (int i = t; i < 1024; i += 512) {
            int r = i >> 4, c = (i & 15) * 8;
            int k = kc + c, n = k >> 6, d = k & 63;
            size_t abase = (((size_t)b * CNH + n) * CL + lb0 + r) * 64 + d;
            *(uint4*)&Ah[r][c] = *(const uint4*)(zh + abase);
            *(uint4*)&Al[r][c] = *(const uint4*)(zl + abase);
        }
        for (int i = t; i < 2048; i += 512) {
            int r = i >> 4, c = (i & 15) * 8;
            *(uint4*)&Bhs[r][c] = *(const uint4*)(Bh + (size_t)(c0 + r) * CD + kc + c);
            *(uint4*)&Bls[r][c] = *(const uint4*)(Bl + (size_t)(c0 + r) * CD + kc + c);
        }
        __syncthreads();
#pragma unroll
        for (int m16 = 0; m16 < 4; ++m16)
#pragma unroll
            for (int ks = 0; ks < 4; ++ks) {
                short8v ah = *(const short8v*)&Ah[m16 * 16 + lm][ks * 32 + lg * 8];
                short8v al = *(const short8v*)&Al[m16 * 16 + lm][ks * 32 + lg * 8];
                short8v bh = *(const short8v*)&Bhs[wv * 16 + lm][ks * 32 + lg * 8];
                short8v bl = *(const short8v*)&Bls[wv * 16 + lm][ks * 32 + lg * 8];
                acc[m16] = MFMA16(ah, bh, acc[m16]);
                acc[m16] = MFMA16(ah, bl, acc[m16]);
                acc[m16] = MFMA16(al, bh, acc[m16]);
            }
        __syncthreads();
    }
    float(*Os)[132] = (float(*)[132])SM;
    {
        int col = wv * 16 + lm;
        float bb = bias[c0 + col];
#pragma unroll
        for (int m16 = 0; m16 < 4; ++m16)
#pragma unroll
            for (int r = 0; r < 4; ++r)
                Os[m16 * 16 + lg * 4 + r][col] = acc[m16][r] + bb;
    }
    __syncthreads();
    for (int i = t; i < 2048; i += 512) {
        int r = i >> 5, c = (i & 31) * 4;
        *(float4*)(C + (size_t)(r0 + r) * CD + c0 + c) = *(const float4*)&Os[r][c];
    }
}

// ---------------------------------------------------------------------------
// lr / log_wd projections: 4 waves, 4 heads per wave.
// ---------------------------------------------------------------------------
__global__ __launch_bounds__(256) void lrwd_kernel(
    const float* __restrict__ x, const float* __restrict__ lblr,
    const float* __restrict__ fclr_w, const float* __restrict__ fclr_b,
    const float* __restrict__ lbwd, const float* __restrict__ fcwd_w,
    const float* __restrict__ fcwd_b, float* __restrict__ lrp,
    float* __restrict__ logwd) {
    const int r = blockIdx.x;
    const int b = r >> 10, l = r & 1023;
    const int wv = threadIdx.x >> 6, lane = threadIdx.x & 63;
    float xv[16];
#pragma unroll
    for (int j = 0; j < 16; ++j) xv[j] = x[(size_t)r * CD + lane + 64 * j];
    for (int j = 0; j < 4; ++j) {
        const int n = wv * 4 + j;
        float d1 = 0.f, d2 = 0.f;
#pragma unroll
        for (int k = 0; k < 16; ++k) {
            d1 += xv[k] * fclr_w[(size_t)n * CD + lane + 64 * k];
            d2 += xv[k] * fcwd_w[(size_t)n * CD + lane + 64 * k];
        }
#pragma unroll
        for (int s = 32; s > 0; s >>= 1) {
            d1 += __shfl_down(d1, s);
            d2 += __shfl_down(d2, s);
        }
        if (lane == 0) {
            lrp[((size_t)b * CNH + n) * CL + l] = __expf(lblr[n]) * sigf(d1 + fclr_b[n]);
            logwd[((size_t)b * CNH + n) * CL + l] =
                log1pf(-__expf(lbwd[n]) * sigf(d2 + fcwd_b[n]));
        }
    }
}

// ---------------------------------------------------------------------------
// Inclusive prefix sum of log_wd -> cum, plus wdc = exp(cum).
// ---------------------------------------------------------------------------
__global__ __launch_bounds__(64) void scan_kernel(float* __restrict__ cum,
                                                  float* __restrict__ wdc) {
    const int bn = blockIdx.x;
    const int lane = threadIdx.x;
    float* p = cum + (size_t)bn * CL;
    float v[16];
#pragma unroll
    for (int j = 0; j < 16; ++j) v[j] = p[lane * 16 + j];
#pragma unroll
    for (int j = 1; j < 16; ++j) v[j] += v[j - 1];
    float tot = v[15];
    float inc = tot;
#pragma unroll
    for (int s = 1; s < 64; s <<= 1) {
        float tv = __shfl_up(inc, s);
        if (lane >= s) inc += tv;
    }
    const float pre = inc - tot;
#pragma unroll
    for (int j = 0; j < 16; ++j) {
        float c = pre + v[j];
        p[lane * 16 + j] = c;
        wdc[(size_t)bn * CL + lane * 16 + j] = __expf(c);
    }
}

// ---------------------------------------------------------------------------
// MFMA MLP fwd/bwd over 64 tokens.
// ---------------------------------------------------------------------------
__global__ __launch_bounds__(256) void mlp_mfma(
    const unsigned short* __restrict__ kbf, const float* __restrict__ vh,
    const unsigned short* __restrict__ w1bf, const unsigned short* __restrict__ w2bf,
    const unsigned short* __restrict__ w2tbf, unsigned short* __restrict__ x2bf,
    unsigned short* __restrict__ x2t, unsigned short* __restrict__ gz1t,
    unsigned short* __restrict__ gz2t) {
    __shared__ __align__(16) unsigned short RA[128][72];
    __shared__ __align__(16) unsigned short RB[64][72];
    __shared__ __align__(16) unsigned short RC[64][136];
    __shared__ __align__(16) unsigned short X2s[64][136];
    const int bn = blockIdx.y, l0 = blockIdx.x << 6;
    const int t = threadIdx.x;
    const int wv = t >> 6, lane = t & 63;
    const int lm = lane & 15, lg = lane >> 4;
    {
        const unsigned short* kg = kbf + ((size_t)bn * CL + l0) * CHD;
        for (int i = t; i < 512; i += 256) {
            int r = i >> 3, c = (i & 7) * 8;
            *(uint4*)&RB[r][c] = *(const uint4*)(kg + (size_t)r * CHD + c);
        }
        const unsigned short* w1g = w1bf + (size_t)bn * CHDH * CHD;
        for (int i = t; i < 1024; i += 256) {
            int r = i >> 3, c = (i & 7) * 8;
            *(uint4*)&RA[r][c] = *(const uint4*)(w1g + (size_t)r * CHD + c);
        }
        const unsigned short* w2g = w2bf + (size_t)bn * CHD * CHDH;
        for (int i = t; i < 1024; i += 256) {
            int r = i >> 4, c = (i & 15) * 8;
            *(uint4*)&RC[r][c] = *(const uint4*)(w2g + (size_t)r * CHDH + c);
        }
    }
    __syncthreads();
    f32x4 acc1[4][2];
#pragma unroll
    for (int i = 0; i < 4; ++i)
#pragma unroll
        for (int j = 0; j < 2; ++j) acc1[i][j] = (f32x4){0.f, 0.f, 0.f, 0.f};
#pragma unroll
    for (int m16 = 0; m16 < 4; ++m16)
#pragma unroll
        for (int hh = 0; hh < 2; ++hh) {
            int h16 = wv * 2 + hh;
#pragma unroll
            for (int ks = 0; ks < 2; ++ks) {
                short8v a = *(const short8v*)&RB[m16 * 16 + lm][ks * 32 + lg * 8];
                short8v b = *(const short8v*)&RA[h16 * 16 + lm][ks * 32 + lg * 8];
                acc1[m16][hh] = MFMA16(a, b, acc1[m16][hh]);
            }
        }
#pragma unroll
    for (int m16 = 0; m16 < 4; ++m16)
#pragma unroll
        for (int hh = 0; hh < 2; ++hh)
#pragma unroll
            for (int r = 0; r < 4; ++r) {
                float a = acc1[m16][hh][r];
                X2s[m16 * 16 + lg * 4 + r][(wv * 2 + hh) * 16 + lm] = f2bf(a * sigf(a));
            }
    __syncthreads();
    {
        const unsigned short* w2tg = w2tbf + (size_t)bn * CHDH * CHD;
        for (int i = t; i < 1024; i += 256) {
            int r = i >> 3, c = (i & 7) * 8;
            *(uint4*)&RA[r][c] = *(const uint4*)(w2tg + (size_t)r * CHD + c);
        }
    }
    {
        f32x4 acc2[4];
#pragma unroll
        for (int i = 0; i < 4; ++i) acc2[i] = (f32x4){0.f, 0.f, 0.f, 0.f};
#pragma unroll
        for (int m16 = 0; m16 < 4; ++m16)
#pragma unroll
            for (int ks = 0; ks < 4; ++ks) {
                short8v a = *(const short8v*)&X2s[m16 * 16 + lm][ks * 32 + lg * 8];
                short8v b = *(const short8v*)&RC[wv * 16 + lm][ks * 32 + lg * 8];
                acc2[m16] = MFMA16(a, b, acc2[m16]);
            }
#pragma unroll
        for (int m16 = 0; m16 < 4; ++m16)
#pragma unroll
            for (int r = 0; r < 4; ++r) {
                int l = l0 + m16 * 16 + lg * 4 + r;
                float v = vh[((size_t)bn * CL + l) * 64 + wv * 16 + lm];
                RB[m16 * 16 + lg * 4 + r][wv * 16 + lm] = f2bf(acc2[m16][r] - v);
            }
    }
    __syncthreads();
#pragma unroll
    for (int m16 = 0; m16 < 4; ++m16)
#pragma unroll
        for (int hh = 0; hh < 2; ++hh) {
            int h16 = wv * 2 + hh;
            f32x4 p = (f32x4){0.f, 0.f, 0.f, 0.f};
#pragma unroll
            for (int ks = 0; ks < 2; ++ks) {
                short8v a = *(const short8v*)&RB[m16 * 16 + lm][ks * 32 + lg * 8];
                short8v b = *(const short8v*)&RA[h16 * 16 + lm][ks * 32 + lg * 8];
                p = MFMA16(a, b, p);
            }
#pragma unroll
            for (int r = 0; r < 4; ++r) {
                float zz = acc1[m16][hh][r];
                float s = sigf(zz);
                float sil = zz * s;
                RC[m16 * 16 + lg * 4 + r][h16 * 16 + lm] =
                    f2bf((sil + s * (1.f - sil)) * p[r]);
            }
        }
    __syncthreads();
    for (int i = t; i < 1024; i += 256) {
        int r = i >> 4, c = (i & 15) * 8;
        *(uint4*)(x2bf + ((size_t)bn * CL + l0 + r) * CHDH + c) = *(const uint4*)&X2s[r][c];
    }
    for (int i = t; i < 1024; i += 256) {
        int h = i >> 3, lb = (i & 7) * 8;
        uint4 u;
        u.x = pkus(X2s[lb + 0][h], X2s[lb + 1][h]);
        u.y = pkus(X2s[lb + 2][h], X2s[lb + 3][h]);
        u.z = pkus(X2s[lb + 4][h], X2s[lb + 5][h]);
        u.w = pkus(X2s[lb + 6][h], X2s[lb + 7][h]);
        *(uint4*)(x2t + ((size_t)bn * CHDH + h) * CL + l0 + lb) = u;
    }
    for (int i = t; i < 1024; i += 256) {
        int h = i >> 3, lb = (i & 7) * 8;
        uint4 u;
        u.x = pkus(RC[lb + 0][h], RC[lb + 1][h]);
        u.y = pkus(RC[lb + 2][h], RC[lb + 3][h]);
        u.z = pkus(RC[lb + 4][h], RC[lb + 5][h]);
        u.w = pkus(RC[lb + 6][h], RC[lb + 7][h]);
        *(uint4*)(gz1t + ((size_t)bn * CHDH + h) * CL + l0 + lb) = u;
    }
    for (int i = t; i < 512; i += 256) {
        int d = i >> 3, lb = (i & 7) * 8;
        uint4 u;
        u.x = pkus(RB[lb + 0][d], RB[lb + 1][d]);
        u.y = pkus(RB[lb + 2][d], RB[lb + 3][d]);
        u.z = pkus(RB[lb + 4][d], RB[lb + 5][d]);
        u.w = pkus(RB[lb + 6][d], RB[lb + 7][d]);
        *(uint4*)(gz2t + ((size_t)bn * CHD + d) * CL + l0 + lb) = u;
    }
}

// ---------------------------------------------------------------------------
// dsA1: per-chunk state delta for layer 1.
// ---------------------------------------------------------------------------
__global__ __launch_bounds__(256) void dsA1(
    const unsigned short* __restrict__ ktbf, const unsigned short* __restrict__ gz1t,
    const float* __restrict__ lrp, const float* __restrict__ cump,
    float* __restrict__ ds1, float* __restrict__ ds2) {
    __shared__ __align__(16) unsigned short Ab[64][72];
    __shared__ __align__(16) unsigned short Bb[128][72];
    __shared__ float coefA[64];
    const int c = blockIdx.x, bn = blockIdx.y, t = threadIdx.x;
    const int l0 = c << 6;
    const int wv = t >> 6, lane = t & 63;
    const int lm = lane & 15, lg = lane >> 4;
    const float Ac = cump[(size_t)bn * CL + l0];
    if (t < 64)
        coefA[t] = lrp[(size_t)bn * CL + l0 + t] *
                   __expf(Ac - cump[(size_t)bn * CL + l0 + t]);
    for (int i = t; i < 1024; i += 256) {
        int h = i >> 3, cc = (i & 7) * 8;
        *(uint4*)&Bb[h][cc] = *(const uint4*)(gz1t + ((size_t)bn * CHDH + h) * CL + l0 + cc);
    }
    __syncthreads();
    for (int i = t; i < 512; i += 256) {
        int d = i >> 3, cc = (i & 7) * 8;
        uint4 g = *(const uint4*)(ktbf + ((size_t)bn * CHD + d) * CL + l0 + cc);
        unsigned short* gp = (unsigned short*)&g;
        uint4 o;
        o.x = pk2(bf2f(gp[0]) * coefA[cc + 0], bf2f(gp[1]) * coefA[cc + 1]);
        o.y = pk2(bf2f(gp[2]) * coefA[cc + 2], bf2f(gp[3]) * coefA[cc + 3]);
        o.z = pk2(bf2f(gp[4]) * coefA[cc + 4], bf2f(gp[5]) * coefA[cc + 5]);
        o.w = pk2(bf2f(gp[6]) * coefA[cc + 6], bf2f(gp[7]) * coefA[cc + 7]);
        *(uint4*)&Ab[d][cc] = o;
    }
    __syncthreads();
    f32x4 acc[8];
#pragma unroll
    for (int i = 0; i < 8; ++i) acc[i] = (f32x4){0.f, 0.f, 0.f, 0.f};
#pragma unroll
    for (int h16 = 0; h16 < 8; ++h16)
#pragma unroll
        for (int ks = 0; ks < 2; ++ks) {
            short8v a = *(const short8v*)&Ab[wv * 16 + lm][ks * 32 + lg * 8];
            short8v b = *(const short8v*)&Bb[h16 * 16 + lm][ks * 32 + lg * 8];
            acc[h16] = MFMA16(a, b, acc[h16]);
        }
    float* og = (bn < 16 ? ds1 : ds2) + ((size_t)(((bn & 15) << 4) + c) << 13);
#pragma unroll
    for (int h16 = 0; h16 < 8; ++h16)
#pragma unroll
        for (int r = 0; r < 4; ++r)
            og[(wv * 16 + lg * 4 + r) * 128 + h16 * 16 + lm] = acc[h16][r];
}

// ---------------------------------------------------------------------------
// dsB1: state prefix scan + emit bf16 prefix states and w1n.
// Grid (8 element-groups, 32 bn).
// ---------------------------------------------------------------------------
__global__ __launch_bounds__(256) void dsB1(
    const float* __restrict__ ds1, const float* __restrict__ ds2,
    const float* __restrict__ cump, const float* __restrict__ W1,
    unsigned short* __restrict__ sp1, float* __restrict__ w1n) {
    __shared__ float anch[16];
    const int g = blockIdx.x, bn = blockIdx.y, t = threadIdx.x;
    if (t < 16) anch[t] = cump[(size_t)bn * CL + (t << 6)];
    __syncthreads();
    const float ccl = cump[(size_t)bn * CL + CL - 1];
    const float wdcl = __expf(ccl);
    const float* dS = (bn < 16 ? ds1 : ds2) + ((size_t)((bn & 15) << 4) << 13);
    unsigned short* spb = sp1 + ((size_t)bn << 17);
    const int e0 = g << 10;
    float s[4];
#pragma unroll
    for (int j = 0; j < 4; ++j) s[j] = 0.f;
    for (int c = 0; c < 16; ++c) {
        if (c > 0) {
            float fac = __expf(anch[c] - anch[c - 1]);
            const float* dp = dS + ((size_t)(c - 1) << 13);
#pragma unroll
            for (int j = 0; j < 4; ++j) s[j] = fac * (s[j] + dp[e0 + j * 256 + t]);
        }
        unsigned short* so = spb + ((size_t)c << 13);
#pragma unroll
        for (int j = 0; j < 4; ++j) so[e0 + j * 256 + t] = f2bf(s[j]);
    }
    const float ex = __expf(ccl - anch[15]);
    const float* dp = dS + ((size_t)15 << 13);
    const float* w1g = W1 + ((size_t)bn << 13);
    float* og = w1n + ((size_t)bn << 13);
#pragma unroll
    for (int j = 0; j < 4; ++j) {
        int e = e0 + j * 256 + t;
        int d = e >> 7, h = e & 127;
        float full = s[j] + dp[e];
        og[h * 64 + d] = wdcl * w1g[h * 64 + d] - ex * full;
    }
}

// ---------------------------------------------------------------------------
// dsC1: per-chunk layer-1 readout.
// ---------------------------------------------------------------------------
__global__ __launch_bounds__(256) void dsC1(
    const unsigned short* __restrict__ qbf, const unsigned short* __restrict__ kbf,
    const unsigned short* __restrict__ gz1t, const unsigned short* __restrict__ w1bf,
    const unsigned short* __restrict__ sp1, const float* __restrict__ lrp,
    const float* __restrict__ cump, const float* __restrict__ wdcp,
    unsigned short* __restrict__ x2q) {
    __shared__ __align__(16) unsigned short Qb[64][72];
    __shared__ __align__(16) unsigned short XB[128][72];
    __shared__ __align__(16) unsigned short Kb[64][72];
    __shared__ __align__(16) unsigned short GT[128][72];
    __shared__ __align__(16) unsigned short Pm[64][72];
    __shared__ float lrc[64], cumc[64], wdcc[64];
    const int c = blockIdx.x, bn = blockIdx.y, t = threadIdx.x;
    const int l0 = c << 6;
    const int w4 = t >> 6, lane = t & 63;
    const int lm = lane & 15, lg = lane >> 4;
    {
        const unsigned short* qg = qbf + ((size_t)bn * CL + l0) * CHD;
        for (int i = t; i < 512; i += 256) {
            int r = i >> 3, cc = (i & 7) * 8;
            *(uint4*)&Qb[r][cc] = *(const uint4*)(qg + (size_t)r * CHD + cc);
        }
        const unsigned short* wg = w1bf + (size_t)bn * CHDH * CHD;
        for (int i = t; i < 1024; i += 256) {
            int r = i >> 3, cc = (i & 7) * 8;
            *(uint4*)&XB[r][cc] = *(const uint4*)(wg + (size_t)r * CHD + cc);
        }
        if (t < 64) {
            lrc[t] = lrp[(size_t)bn * CL + l0 + t];
            cumc[t] = cump[(size_t)bn * CL + l0 + t];
            wdcc[t] = wdcp[(size_t)bn * CL + l0 + t];
        }
    }
    __syncthreads();
    const float Ac = cumc[0];
    short8v qf[4][2];
#pragma unroll
    for (int m16 = 0; m16 < 4; ++m16)
#pragma unroll
        for (int ks = 0; ks < 2; ++ks)
            qf[m16][ks] = *(const short8v*)&Qb[m16 * 16 + lm][ks * 32 + lg * 8];
    f32x4 acc[4][2];
#pragma unroll
    for (int i = 0; i < 4; ++i)
#pragma unroll
        for (int j = 0; j < 2; ++j) acc[i][j] = (f32x4){0.f, 0.f, 0.f, 0.f};
    {
        short8v wf[2][2];
#pragma unroll
        for (int hh = 0; hh < 2; ++hh)
#pragma unroll
            for (int ks = 0; ks < 2; ++ks)
                wf[hh][ks] =
                    *(const short8v*)&XB[(w4 * 2 + hh) * 16 + lm][ks * 32 + lg * 8];
#pragma unroll
        for (int m16 = 0; m16 < 4; ++m16)
#pragma unroll
            for (int hh = 0; hh < 2; ++hh)
#pragma unroll
                for (int ks = 0; ks < 2; ++ks)
                    acc[m16][hh] = MFMA16(qf[m16][ks], wf[hh][ks], acc[m16][hh]);
#pragma unroll
        for (int m16 = 0; m16 < 4; ++m16)
#pragma unroll
            for (int r = 0; r < 4; ++r) {
                float w = wdcc[m16 * 16 + lg * 4 + r];
                acc[m16][0][r] *= w;
                acc[m16][1][r] *= w;
            }
    }
    __syncthreads();
    {
        const unsigned short* sb = sp1 + ((((size_t)bn << 4) + c) << 13);
        for (int i = t; i < 1024; i += 256) {
            int d = i >> 4, hg = (i & 15) * 8;
            uint4 u = *(const uint4*)(sb + d * 128 + hg);
            const unsigned short* up = (const unsigned short*)&u;
#pragma unroll
            for (int j = 0; j < 8; ++j) XB[hg + j][d] = up[j];
        }
    }
    __syncthreads();
    {
        short8v sf[2][2];
#pragma unroll
        for (int hh = 0; hh < 2; ++hh)
#pragma unroll
            for (int ks = 0; ks < 2; ++ks)
                sf[hh][ks] =
                    *(const short8v*)&XB[(w4 * 2 + hh) * 16 + lm][ks * 32 + lg * 8];
#pragma unroll
        for (int m16 = 0; m16 < 4; ++m16)
#pragma unroll
            for (int hh = 0; hh < 2; ++hh) {
                f32x4 pf = (f32x4){0.f, 0.f, 0.f, 0.f};
#pragma unroll
                for (int ks = 0; ks < 2; ++ks)
                    pf = MFMA16(qf[m16][ks], sf[hh][ks], pf);
#pragma unroll
                for (int r = 0; r < 4; ++r) {
                    float em = __expf(cumc[m16 * 16 + lg * 4 + r] - Ac);
                    acc[m16][hh][r] -= em * pf[r];
                }
            }
    }
    __syncthreads();
    {
        const unsigned short* kg = kbf + ((size_t)bn * CL + l0) * CHD;
        for (int i = t; i < 512; i += 256) {
            int r = i >> 3, cc = (i & 7) * 8;
            *(uint4*)&Kb[r][cc] = *(const uint4*)(kg + (size_t)r * CHD + cc);
        }
        const unsigned short* gg = gz1t + (size_t)bn * CHDH * CL + l0;
        for (int i = t; i < 1024; i += 256) {
            int r = i >> 3, cc = (i & 7) * 8;
            *(uint4*)&GT[r][cc] = *(const uint4*)(gg + (size_t)r * CL + cc);
        }
    }
    __syncthreads();
    {
        short8v kf[2];
#pragma unroll
        for (int ks = 0; ks < 2; ++ks)
            kf[ks] = *(const short8v*)&Kb[w4 * 16 + lm][ks * 32 + lg * 8];
#pragma unroll
        for (int m16 = 0; m16 < 4; ++m16) {
            f32x4 s = (f32x4){0.f, 0.f, 0.f, 0.f};
#pragma unroll
            for (int ks = 0; ks < 2; ++ks) s = MFMA16(kf[ks], qf[m16][ks], s);
            int mloc = m16 * 16 + lm;
            float cm = cumc[mloc];
            unsigned short pv[4];
#pragma unroll
            for (int r = 0; r < 4; ++r) {
                int lloc = w4 * 16 + lg * 4 + r;
                float val = (mloc >= lloc)
                                ? s[r] * lrc[lloc] * __expf(cm - cumc[lloc])
                                : 0.f;
                pv[r] = f2bf(val);
            }
            *(uint2*)&Pm[mloc][w4 * 16 + lg * 4] =
                make_uint2(pkus(pv[0], pv[1]), pkus(pv[2], pv[3]));
        }
    }
    __syncthreads();
    {
        short8v gt[2][2], pm[4][2];
#pragma unroll
        for (int hh = 0; hh < 2; ++hh)
#pragma unroll
            for (int ks = 0; ks < 2; ++ks)
                gt[hh][ks] =
                    *(const short8v*)&GT[(w4 * 2 + hh) * 16 + lm][ks * 32 + lg * 8];
#pragma unroll
        for (int m16 = 0; m16 < 4; ++m16)
#pragma unroll
            for (int ks = 0; ks < 2; ++ks)
                pm[m16][ks] = *(const short8v*)&Pm[m16 * 16 + lm][ks * 32 + lg * 8];
#pragma unroll
        for (int m16 = 0; m16 < 4; ++m16)
#pragma unroll
            for (int hh = 0; hh < 2; ++hh) {
                f32x4 pf = (f32x4){0.f, 0.f, 0.f, 0.f};
#pragma unroll
                for (int ks = 0; ks < 2; ++ks) pf = MFMA16(pm[m16][ks], gt[hh][ks], pf);
#pragma unroll
                for (int r = 0; r < 4; ++r) acc[m16][hh][r] -= pf[r];
            }
    }
    __syncthreads();
    {
        unsigned short(*Ob)[136] = (unsigned short(*)[136])XB;
#pragma unroll
        for (int m16 = 0; m16 < 4; ++m16)
#pragma unroll
            for (int hh = 0; hh < 2; ++hh) {
                int h = (w4 * 2 + hh) * 16 + lm;
#pragma unroll
                for (int r = 0; r < 4; ++r) {
                    float a = acc[m16][hh][r];
                    Ob[m16 * 16 + lg * 4 + r][h] = f2bf(a * sigf(a));
                }
            }
        __syncthreads();
        unsigned short* og = x2q + ((size_t)bn * CL + l0) * CHDH;
        for (int i = t; i < 1024; i += 256) {
            int r = i >> 4, cc = (i & 15) * 8;
            *(uint4*)(og + (size_t)r * CHDH + cc) = *(const uint4*)&Ob[r][cc];
        }
    }
}

// ---------------------------------------------------------------------------
// dsA2: per-chunk state delta for layer 2.
// ---------------------------------------------------------------------------
__global__ __launch_bounds__(256) void dsA2(
    const unsigned short* __restrict__ x2t, const unsigned short* __restrict__ gz2t,
    const float* __restrict__ lrp, const float* __restrict__ cump,
    float* __restrict__ ds1, float* __restrict__ ds2) {
    __shared__ __align__(16) unsigned short Ab[128][72];
    __shared__ __align__(16) unsigned short Bb[64][72];
    __shared__ float coefA[64];
    const int c = blockIdx.x, bn = blockIdx.y, t = threadIdx.x;
    const int l0 = c << 6;
    const int wv = t >> 6, lane = t & 63;
    const int lm = lane & 15, lg = lane >> 4;
    const float Ac = cump[(size_t)bn * CL + l0];
    if (t < 64)
        coefA[t] = lrp[(size_t)bn * CL + l0 + t] *
                   __expf(Ac - cump[(size_t)bn * CL + l0 + t]);
    for (int i = t; i < 512; i += 256) {
        int d = i >> 3, cc = (i & 7) * 8;
        *(uint4*)&Bb[d][cc] = *(const uint4*)(gz2t + ((size_t)bn * CHD + d) * CL + l0 + cc);
    }
    __syncthreads();
    for (int i = t; i < 1024; i += 256) {
        int h = i >> 3, cc = (i & 7) * 8;
        uint4 g = *(const uint4*)(x2t + ((size_t)bn * CHDH + h) * CL + l0 + cc);
        unsigned short* gp = (unsigned short*)&g;
        uint4 o;
        o.x = pk2(bf2f(gp[0]) * coefA[cc + 0], bf2f(gp[1]) * coefA[cc + 1]);
        o.y = pk2(bf2f(gp[2]) * coefA[cc + 2], bf2f(gp[3]) * coefA[cc + 3]);
        o.z = pk2(bf2f(gp[4]) * coefA[cc + 4], bf2f(gp[5]) * coefA[cc + 5]);
        o.w = pk2(bf2f(gp[6]) * coefA[cc + 6], bf2f(gp[7]) * coefA[cc + 7]);
        *(uint4*)&Ab[h][cc] = o;
    }
    __syncthreads();
    f32x4 acc[2][4];
#pragma unroll
    for (int i = 0; i < 2; ++i)
#pragma unroll
        for (int j = 0; j < 4; ++j) acc[i][j] = (f32x4){0.f, 0.f, 0.f, 0.f};
#pragma unroll
    for (int mm = 0; mm < 2; ++mm) {
        int hk16 = wv * 2 + mm;
#pragma unroll
        for (int d16 = 0; d16 < 4; ++d16)
#pragma unroll
            for (int ks = 0; ks < 2; ++ks) {
                short8v a = *(const short8v*)&Ab[hk16 * 16 + lm][ks * 32 + lg * 8];
                short8v b = *(const short8v*)&Bb[d16 * 16 + lm][ks * 32 + lg * 8];
                acc[mm][d16] = MFMA16(a, b, acc[mm][d16]);
            }
    }
    float* og = (bn < 16 ? ds1 : ds2) + ((size_t)(((bn & 15) << 4) + c) << 13);
#pragma unroll
    for (int mm = 0; mm < 2; ++mm)
#pragma unroll
        for (int d16 = 0; d16 < 4; ++d16)
#pragma unroll
            for (int r = 0; r < 4; ++r)
                og[((wv * 2 + mm) * 16 + lg * 4 + r) * 64 + d16 * 16 + lm] =
                    acc[mm][d16][r];
}

// ---------------------------------------------------------------------------
// dsB2: scan for layer 2 + w2n. Grid (8 element-groups, 32 bn).
// ---------------------------------------------------------------------------
__global__ __launch_bounds__(256) void dsB2(
    const float* __restrict__ ds1, const float* __restrict__ ds2,
    const float* __restrict__ cump, const float* __restrict__ W2,
    unsigned short* __restrict__ sp2, float* __restrict__ w2n) {
    __shared__ float anch[16];
    const int g = blockIdx.x, bn = blockIdx.y, t = threadIdx.x;
    if (t < 16) anch[t] = cump[(size_t)bn * CL + (t << 6)];
    __syncthreads();
    const float ccl = cump[(size_t)bn * CL + CL - 1];
    const float wdcl = __expf(ccl);
    const float* dS = (bn < 16 ? ds1 : ds2) + ((size_t)((bn & 15) << 4) << 13);
    unsigned short* spb = sp2 + ((size_t)bn << 17);
    const int e0 = g << 10;
    float s[4];
#pragma unroll
    for (int j = 0; j < 4; ++j) s[j] = 0.f;
    for (int c = 0; c < 16; ++c) {
        if (c > 0) {
            float fac = __expf(anch[c] - anch[c - 1]);
            const float* dp = dS + ((size_t)(c - 1) << 13);
#pragma unroll
            for (int j = 0; j < 4; ++j) s[j] = fac * (s[j] + dp[e0 + j * 256 + t]);
        }
        unsigned short* so = spb + ((size_t)c << 13);
#pragma unroll
        for (int j = 0; j < 4; ++j) so[e0 + j * 256 + t] = f2bf(s[j]);
    }
    const float ex = __expf(ccl - anch[15]);
    const float* dp = dS + ((size_t)15 << 13);
    const float* w2g = W2 + ((size_t)bn << 13);
    float* og = w2n + ((size_t)bn << 13);
#pragma unroll
    for (int j = 0; j < 4; ++j) {
        int e = e0 + j * 256 + t;
        int hk = e >> 6, d = e & 63;
        float full = s[j] + dp[e];
        og[d * 128 + hk] = wdcl * w2g[d * 128 + hk] - ex * full;
    }
}

// ---------------------------------------------------------------------------
// dsC2: per-chunk layer-2 readout. Emits z2s as pre-split hi/lo bf16.
// ---------------------------------------------------------------------------
__global__ __launch_bounds__(256) void dsC2(
    const unsigned short* __restrict__ x2q, const unsigned short* __restrict__ x2bf,
    const unsigned short* __restrict__ gz2t, const unsigned short* __restrict__ w2bf,
    const unsigned short* __restrict__ sp2, const float* __restrict__ lrp,
    const float* __restrict__ cump, const float* __restrict__ wdcp,
    unsigned short* __restrict__ zh, unsigned short* __restrict__ zl) {
    __shared__ __align__(16) unsigned short X2qb[64][136];
    __shared__ __align__(16) unsigned short XB[64][136];
    __shared__ __align__(16) unsigned short GT2[64][72];
    __shared__ __align__(16) unsigned short Pm[64][72];
    __shared__ float lrc[64], cumc[64], wdcc[64];
    const int c = blockIdx.x, bn = blockIdx.y, t = threadIdx.x;
    const int l0 = c << 6;
    const int w4 = t >> 6, lane = t & 63;
    const int lm = lane & 15, lg = lane >> 4;
    {
        const unsigned short* qg = x2q + ((size_t)bn * CL + l0) * CHDH;
        for (int i = t; i < 1024; i += 256) {
            int r = i >> 4, cc = (i & 15) * 8;
            *(uint4*)&X2qb[r][cc] = *(const uint4*)(qg + (size_t)r * CHDH + cc);
        }
        const unsigned short* wg = w2bf + (size_t)bn * CHD * CHDH;
        for (int i = t; i < 1024; i += 256) {
            int r = i >> 4, cc = (i & 15) * 8;
            *(uint4*)&XB[r][cc] = *(const uint4*)(wg + (size_t)r * CHDH + cc);
        }
        if (t < 64) {
            lrc[t] = lrp[(size_t)bn * CL + l0 + t];
            cumc[t] = cump[(size_t)bn * CL + l0 + t];
            wdcc[t] = wdcp[(size_t)bn * CL + l0 + t];
        }
    }
    __syncthreads();
    const float Ac = cumc[0];
    short8v qf[4][4];
#pragma unroll
    for (int m16 = 0; m16 < 4; ++m16)
#pragma unroll
        for (int ks = 0; ks < 4; ++ks)
            qf[m16][ks] = *(const short8v*)&X2qb[m16 * 16 + lm][ks * 32 + lg * 8];
    f32x4 acc[4];
#pragma unroll
    for (int i = 0; i < 4; ++i) acc[i] = (f32x4){0.f, 0.f, 0.f, 0.f};
    {
        short8v wf[4];
#pragma unroll
        for (int ks = 0; ks < 4; ++ks)
            wf[ks] = *(const short8v*)&XB[w4 * 16 + lm][ks * 32 + lg * 8];
#pragma unroll
        for (int m16 = 0; m16 < 4; ++m16)
#pragma unroll
            for (int ks = 0; ks < 4; ++ks)
                acc[m16] = MFMA16(qf[m16][ks], wf[ks], acc[m16]);
#pragma unroll
        for (int m16 = 0; m16 < 4; ++m16)
#pragma unroll
            for (int r = 0; r < 4; ++r)
                acc[m16][r] *= wdcc[m16 * 16 + lg * 4 + r];
    }
    __syncthreads();
    {
        const unsigned short* sb = sp2 + ((((size_t)bn << 4) + c) << 13);
        for (int i = t; i < 1024; i += 256) {
            int hk = i >> 3, dg = (i & 7) * 8;
            uint4 u = *(const uint4*)(sb + hk * 64 + dg);
            const unsigned short* up = (const unsigned short*)&u;
#pragma unroll
            for (int j = 0; j < 8; ++j) XB[dg + j][hk] = up[j];
        }
    }
    __syncthreads();
    {
        short8v sf[4];
#pragma unroll
        for (int ks = 0; ks < 4; ++ks)
            sf[ks] = *(const short8v*)&XB[w4 * 16 + lm][ks * 32 + lg * 8];
#pragma unroll
        for (int m16 = 0; m16 < 4; ++m16) {
            f32x4 pf = (f32x4){0.f, 0.f, 0.f, 0.f};
#pragma unroll
            for (int ks = 0; ks < 4; ++ks) pf = MFMA16(qf[m16][ks], sf[ks], pf);
#pragma unroll
            for (int r = 0; r < 4; ++r) {
                float em = __expf(cumc[m16 * 16 + lg * 4 + r] - Ac);
                acc[m16][r] -= em * pf[r];
            }
        }
    }
    __syncthreads();
    {
        const unsigned short* kg = x2bf + ((size_t)bn * CL + l0) * CHDH;
        for (int i = t; i < 1024; i += 256) {
            int r = i >> 4, cc = (i & 15) * 8;
            *(uint4*)&XB[r][cc] = *(const uint4*)(kg + (size_t)r * CHDH + cc);
        }
        const unsigned short* gg = gz2t + (size_t)bn * CHD * CL + l0;
        for (int i = t; i < 512; i += 256) {
            int r = i >> 3, cc = (i & 7) * 8;
            *(uint4*)&GT2[r][cc] = *(const uint4*)(gg + (size_t)r * CL + cc);
        }
    }
    __syncthreads();
    {
        short8v kf[4];
#pragma unroll
        for (int ks = 0; ks < 4; ++ks)
            kf[ks] = *(const short8v*)&XB[w4 * 16 + lm][ks * 32 + lg * 8];
#pragma unroll
        for (int m16 = 0; m16 < 4; ++m16) {
            f32x4 s = (f32x4){0.f, 0.f, 0.f, 0.f};
#pragma unroll
            for (int ks = 0; ks < 4; ++ks) s = MFMA16(kf[ks], qf[m16][ks], s);
            int mloc = m16 * 16 + lm;
            float cm = cumc[mloc];
            unsigned short pv[4];
#pragma unroll
            for (int r = 0; r < 4; ++r) {
                int lloc = w4 * 16 + lg * 4 + r;
                float val = (mloc >= lloc)
                                ? s[r] * lrc[lloc] * __expf(cm - cumc[lloc])
                                : 0.f;
                pv[r] = f2bf(val);
            }
            *(uint2*)&Pm[mloc][w4 * 16 + lg * 4] =
                make_uint2(pkus(pv[0], pv[1]), pkus(pv[2], pv[3]));
        }
    }
    __syncthreads();
    {
        short8v gt[2], pm[4][2];
#pragma unroll
        for (int ks = 0; ks < 2; ++ks)
            gt[ks] = *(const short8v*)&GT2[w4 * 16 + lm][ks * 32 + lg * 8];
#pragma unroll
        for (int m16 = 0; m16 < 4; ++m16)
#pragma unroll
            for (int ks = 0; ks < 2; ++ks)
                pm[m16][ks] = *(const short8v*)&Pm[m16 * 16 + lm][ks * 32 + lg * 8];
#pragma unroll
        for (int m16 = 0; m16 < 4; ++m16) {
            f32x4 pf = (f32x4){0.f, 0.f, 0.f, 0.f};
#pragma unroll
            for (int ks = 0; ks < 2; ++ks) pf = MFMA16(pm[m16][ks], gt[ks], pf);
#pragma unroll
            for (int r = 0; r < 4; ++r) acc[m16][r] -= pf[r];
        }
    }
    __syncthreads();
    {  // store pre-split hi/lo bf16 via fp32 LDS bounce
        float(*Os)[68] = (float(*)[68])X2qb;
#pragma unroll
        for (int m16 = 0; m16 < 4; ++m16)
#pragma unroll
            for (int r = 0; r < 4; ++r)
                Os[m16 * 16 + lg * 4 + r][w4 * 16 + lm] = acc[m16][r];
        __syncthreads();
        unsigned short* zhg = zh + ((size_t)bn * CL + l0) * CHD;
        unsigned short* zlg = zl + ((size_t)bn * CL + l0) * CHD;
        for (int i = t; i < 1024; i += 256) {
            int r = i >> 4, cc = (i & 15) << 2;
            float4 v = *(const float4*)&Os[r][cc];
            unsigned short h0 = f2bf(v.x), h1 = f2bf(v.y), h2 = f2bf(v.z), h3 = f2bf(v.w);
            *(uint2*)(zhg + (size_t)r * CHD + cc) = make_uint2(pkus(h0, h1), pkus(h2, h3));
            *(uint2*)(zlg + (size_t)r * CHD + cc) = make_uint2(
                pk2(v.x - bf2f(h0), v.y - bf2f(h1)), pk2(v.z - bf2f(h2), v.w - bf2f(h3)));
        }
    }
}

// ---------------------------------------------------------------------------
extern "C" void kernel_launch(void* const* d_in, const int* in_sizes, int n_in,
                              void* d_out, int out_size, void* d_ws, size_t ws_size,
                              hipStream_t stream) {
    (void)in_sizes; (void)n_in; (void)out_size; (void)ws_size;
    const float* x      = (const float*)d_in[0];
    const float* W1     = (const float*)d_in[1];
    const float* W2     = (const float*)d_in[2];
    const float* lblr   = (const float*)d_in[3];
    const float* fclr_w = (const float*)d_in[4];
    const float* fclr_b = (const float*)d_in[5];
    const float* lbwd   = (const float*)d_in[6];
    const float* fcwd_w = (const float*)d_in[7];
    const float* fcwd_b = (const float*)d_in[8];
    const float* qw = (const float*)d_in[9];
    const float* qb = (const float*)d_in[10];
    const float* kw = (const float*)d_in[11];
    const float* kb = (const float*)d_in[12];
    const float* vw = (const float*)d_in[13];
    const float* vb = (const float*)d_in[14];
    const float* ow = (const float*)d_in[15];
    const float* ob = (const float*)d_in[16];

    float* ws = (float*)d_ws;
    const size_t SZ_HD = (size_t)CBN * CL * CHD;
    const size_t SZ_HDH = (size_t)CBN * CL * CHDH;
    float* qh   = ws;
    float* khb  = qh + SZ_HD;
    float* vhb  = khb + SZ_HD;
    float* gz2b = vhb + SZ_HD;
    float* z2sb = gz2b + SZ_HD;
    float* x2b  = z2sb + SZ_HD;
    float* gz1b = x2b + SZ_HDH;
    float* x2qb = gz1b + SZ_HDH;
    float* lrb  = x2qb + SZ_HDH;
    float* cumb = lrb + (size_t)CBN * CL;
    float* wdcb = cumb + (size_t)CBN * CL;
    unsigned short* xbf  = (unsigned short*)(wdcb + (size_t)CBN * CL);
    unsigned short* qwbf = xbf + (size_t)CB * CL * CD;
    unsigned short* kwbf = qwbf + (size_t)CD * CD;
    unsigned short* vwbf = kwbf + (size_t)CD * CD;
    unsigned short* owh  = vwbf + (size_t)CD * CD;
    unsigned short* owl  = owh + (size_t)CD * CD;

    unsigned short* qbf   = (unsigned short*)qh;
    unsigned short* kbf   = qbf + SZ_HD;
    unsigned short* ktbf  = (unsigned short*)khb;
    unsigned short* w1bf  = ktbf + SZ_HD;
    unsigned short* w2bf  = w1bf + (size_t)CBN * CHDH * CHD;
    unsigned short* w2tbf = w2bf + (size_t)CBN * CHDH * CHD;
    unsigned short* gz2t  = (unsigned short*)gz2b;
    unsigned short* x2t   = (unsigned short*)x2b;
    unsigned short* gz1t  = (unsigned short*)gz1b;
    unsigned short* x2q   = (unsigned short*)x2qb;
    unsigned short* x2bf  = x2q + SZ_HDH;
    float* ds1 = gz1b + 2097152;
    float* ds2 = x2b + 2097152;
    unsigned short* sp1 = (unsigned short*)vhb;
    unsigned short* sp2 = (unsigned short*)vhb;
    unsigned short* zh = (unsigned short*)z2sb;  // z2s hi bf16 (4 MB)
    unsigned short* zl = zh + SZ_HD;             // z2s lo bf16 (4 MB)

    float* outp = (float*)d_out;
    float* w1n = outp + (size_t)CB * CL * CD;
    float* w2n = w1n + (size_t)CBN * CHDH * CHD;

    conv_kernel<<<6912, 256, 0, stream>>>(x, qw, kw, vw, W1, W2, ow, xbf, qwbf, kwbf,
                                          vwbf, w1bf, w2bf, w2tbf, owh, owl);
    qkv_mfma<<<dim3(24, 32), 512, 0, stream>>>(xbf, qwbf, qb, kb, vb, qbf, kbf, ktbf,
                                               vhb);
    lrwd_kernel<<<CB * CL, 256, 0, stream>>>(x, lblr, fclr_w, fclr_b, lbwd, fcwd_w,
                                             fcwd_b, lrb, cumb);
    scan_kernel<<<CBN, 64, 0, stream>>>(cumb, wdcb);
    mlp_mfma<<<dim3(CL / 64, CBN), 256, 0, stream>>>(kbf, vhb, w1bf, w2bf, w2tbf,
                                                     x2bf, x2t, gz1t, gz2t);
    dsA1<<<dim3(16, CBN), 256, 0, stream>>>(ktbf, gz1t, lrb, cumb, ds1, ds2);
    dsB1<<<dim3(8, CBN), 256, 0, stream>>>(ds1, ds2, cumb, W1, sp1, w1n);
    dsC1<<<dim3(16, CBN), 256, 0, stream>>>(qbf, kbf, gz1t, w1bf, sp1, lrb, cumb,
                                            wdcb, x2q);
    dsA2<<<dim3(16, CBN), 256, 0, stream>>>(x2t, gz2t, lrb, cumb, ds1, ds2);
    dsB2<<<dim3(8, CBN), 256, 0, stream>>>(ds1, ds2, cumb, W2, sp2, w2n);
    dsC2<<<dim3(16, CBN), 256, 0, stream>>>(x2q, x2bf, gz2t, w2bf, sp2, lrb, cumb,
                                            wdcb, zh, zl);
    gemm_obf<<<dim3(32, 8), 512, 0, stream>>>(zh, zl, owh, owl, ob, outp);
}